// Round 1
// baseline (486.485 us; speedup 1.0000x reference)
//
#include <hip/hip_runtime.h>

// Problem constants
#define BB 4
#define SS 2048
#define EE 512
#define HH 8
#define DKK 64
#define NQQ 8
#define BS (BB * SS)   // 8192 rows

// ---------------------------------------------------------------------------
// Kernel A: fused Q/K projection + cos. Only the first NQ=8 features per head
// are ever used, i.e. weight columns h*64 + (0..7). Output qm/km: [B*H][S][8].
// Block: 64 rows x 64 "packed cols" (8 heads x 8 feats), 256 threads, 4x4/thread.
// ---------------------------------------------------------------------------
__global__ __launch_bounds__(256) void qk_proj_kernel(
    const float* __restrict__ x,
    const float* __restrict__ Wq, const float* __restrict__ bq,
    const float* __restrict__ Wk, const float* __restrict__ bk,
    float* __restrict__ qm, float* __restrict__ km)
{
    __shared__ float xs[64][36];     // stride 36: 16B-aligned rows, 2-way max
    __shared__ float wqs[32][64];
    __shared__ float wks[32][64];

    const int tid = threadIdx.x;
    const int tx = tid & 15, ty = tid >> 4;
    const int row0 = blockIdx.x * 64;
    const int c4 = 4 * tx;                              // packed col base
    const int wcol = ((c4 >> 3) << 6) | (c4 & 7);       // real weight col

    float accq[4][4] = {{0.f}};
    float acck[4][4] = {{0.f}};

    for (int k0 = 0; k0 < EE; k0 += 32) {
        __syncthreads();
        // x tile: 64 rows x 32 k  (512 float4)
        #pragma unroll
        for (int it = 0; it < 2; ++it) {
            int idx = tid + it * 256;
            int r = idx >> 3;
            int kk = (idx & 7) << 2;
            *reinterpret_cast<float4*>(&xs[r][kk]) =
                *reinterpret_cast<const float4*>(&x[(size_t)(row0 + r) * EE + k0 + kk]);
        }
        // Wq/Wk tiles: 32 k x 64 packed cols (packed col c -> wcol)
        #pragma unroll
        for (int it = 0; it < 2; ++it) {
            int idx = tid + it * 256;
            int kk = idx >> 4;
            int cc4 = (idx & 15) << 2;
            int wc = ((cc4 >> 3) << 6) | (cc4 & 7);
            *reinterpret_cast<float4*>(&wqs[kk][cc4]) =
                *reinterpret_cast<const float4*>(&Wq[(size_t)(k0 + kk) * EE + wc]);
            *reinterpret_cast<float4*>(&wks[kk][cc4]) =
                *reinterpret_cast<const float4*>(&Wk[(size_t)(k0 + kk) * EE + wc]);
        }
        __syncthreads();
        #pragma unroll 8
        for (int k = 0; k < 32; ++k) {
            float a[4];
            #pragma unroll
            for (int r = 0; r < 4; ++r) a[r] = xs[4 * ty + r][k];
            float4 qv = *reinterpret_cast<const float4*>(&wqs[k][c4]);
            float4 kv = *reinterpret_cast<const float4*>(&wks[k][c4]);
            #pragma unroll
            for (int r = 0; r < 4; ++r) {
                accq[r][0] += a[r] * qv.x; accq[r][1] += a[r] * qv.y;
                accq[r][2] += a[r] * qv.z; accq[r][3] += a[r] * qv.w;
                acck[r][0] += a[r] * kv.x; acck[r][1] += a[r] * kv.y;
                acck[r][2] += a[r] * kv.z; acck[r][3] += a[r] * kv.w;
            }
        }
    }

    const int h = c4 >> 3;
    const int j0 = c4 & 7;   // 0 or 4, float4-aligned within the 8-wide row
    const float4 bqv = *reinterpret_cast<const float4*>(&bq[wcol]);
    const float4 bkv = *reinterpret_cast<const float4*>(&bk[wcol]);
    #pragma unroll
    for (int r = 0; r < 4; ++r) {
        int row = row0 + 4 * ty + r;
        int b = row >> 11;        // / 2048
        int s = row & 2047;
        size_t base = (((size_t)(b * HH + h)) * SS + s) * NQQ + j0;
        float4 oq, ok;
        oq.x = __cosf(accq[r][0] + bqv.x); oq.y = __cosf(accq[r][1] + bqv.y);
        oq.z = __cosf(accq[r][2] + bqv.z); oq.w = __cosf(accq[r][3] + bqv.w);
        ok.x = __cosf(acck[r][0] + bkv.x); ok.y = __cosf(acck[r][1] + bkv.y);
        ok.z = __cosf(acck[r][2] + bkv.z); ok.w = __cosf(acck[r][3] + bkv.w);
        *reinterpret_cast<float4*>(&qm[base]) = oq;
        *reinterpret_cast<float4*>(&km[base]) = ok;
    }
}

// ---------------------------------------------------------------------------
// Kernel B/D: GEMM out = A[8192,512] @ W[512,512] + bias.
// VLAYOUT=1: write to [B,H,S,DK] (V projection); VLAYOUT=0: write [B,S,E].
// Block: 64x64 tile, 256 threads, 4x4 per thread, K-step 32.
// ---------------------------------------------------------------------------
template<int VLAYOUT>
__global__ __launch_bounds__(256) void gemm_bias_kernel(
    const float* __restrict__ A, const float* __restrict__ W,
    const float* __restrict__ bias, float* __restrict__ out)
{
    __shared__ float xs[64][36];
    __shared__ float wst[32][64];

    const int tid = threadIdx.x;
    const int tx = tid & 15, ty = tid >> 4;
    const int row0 = blockIdx.x * 64;
    const int col0 = blockIdx.y * 64;

    float acc[4][4] = {{0.f}};

    for (int k0 = 0; k0 < EE; k0 += 32) {
        __syncthreads();
        #pragma unroll
        for (int it = 0; it < 2; ++it) {
            int idx = tid + it * 256;
            int r = idx >> 3;
            int kk = (idx & 7) << 2;
            *reinterpret_cast<float4*>(&xs[r][kk]) =
                *reinterpret_cast<const float4*>(&A[(size_t)(row0 + r) * EE + k0 + kk]);
        }
        #pragma unroll
        for (int it = 0; it < 2; ++it) {
            int idx = tid + it * 256;
            int kk = idx >> 4;
            int cc4 = (idx & 15) << 2;
            *reinterpret_cast<float4*>(&wst[kk][cc4]) =
                *reinterpret_cast<const float4*>(&W[(size_t)(k0 + kk) * EE + col0 + cc4]);
        }
        __syncthreads();
        #pragma unroll 8
        for (int k = 0; k < 32; ++k) {
            float a[4];
            #pragma unroll
            for (int r = 0; r < 4; ++r) a[r] = xs[4 * ty + r][k];
            float4 wv = *reinterpret_cast<const float4*>(&wst[k][4 * tx]);
            #pragma unroll
            for (int r = 0; r < 4; ++r) {
                acc[r][0] += a[r] * wv.x; acc[r][1] += a[r] * wv.y;
                acc[r][2] += a[r] * wv.z; acc[r][3] += a[r] * wv.w;
            }
        }
    }

    const float4 bv = *reinterpret_cast<const float4*>(&bias[col0 + 4 * tx]);
    #pragma unroll
    for (int r = 0; r < 4; ++r) {
        int row = row0 + 4 * ty + r;
        float4 o;
        o.x = acc[r][0] + bv.x; o.y = acc[r][1] + bv.y;
        o.z = acc[r][2] + bv.z; o.w = acc[r][3] + bv.w;
        if (VLAYOUT) {
            int b = row >> 11;
            int s = row & 2047;
            int h = col0 >> 6;    // 64-col tile == exactly one head
            size_t off = (((size_t)(b * HH + h)) * SS + s) * DKK + 4 * tx;
            *reinterpret_cast<float4*>(&out[off]) = o;
        } else {
            *reinterpret_cast<float4*>(&out[(size_t)row * EE + col0 + 4 * tx]) = o;
        }
    }
}

// ---------------------------------------------------------------------------
// Kernel C: attention. sim = qm . km^T (inner dim 8), sim in [-8,8] so softmax
// needs no max subtraction: w = exp(sim), out = (w @ V) / rowsum(w).
// Block: one (b,h), 64 q-rows; iterate 32 k-tiles of 64.
// ---------------------------------------------------------------------------
__global__ __launch_bounds__(256) void attn_kernel(
    const float* __restrict__ qm, const float* __restrict__ km,
    const float* __restrict__ V, float* __restrict__ att)
{
    __shared__ float kms[64][9];       // stride 9: 2-way max on scalar reads
    __shared__ float vtile[64][64];    // stride 64: 2-way on b128 reads
    __shared__ float wsh[64][68];      // stride 68: 16B-aligned, 2-way on b128
    __shared__ float zred[16][64];
    __shared__ float zinv[64];

    const int tid = threadIdx.x;
    const int tx = tid & 15, ty = tid >> 4;
    const int q0 = blockIdx.x * 64;
    const int bh = blockIdx.y;
    const float* __restrict__ qmb = qm + (size_t)bh * SS * NQQ;
    const float* __restrict__ kmb = km + (size_t)bh * SS * NQQ;
    const float* __restrict__ Vb  = V  + (size_t)bh * SS * DKK;

    // this thread's 4 q-rows (loop-invariant) into registers
    float qreg[4][8];
    #pragma unroll
    for (int r = 0; r < 4; ++r) {
        float4 a = *reinterpret_cast<const float4*>(&qmb[(size_t)(q0 + 4 * ty + r) * NQQ]);
        float4 b = *reinterpret_cast<const float4*>(&qmb[(size_t)(q0 + 4 * ty + r) * NQQ + 4]);
        qreg[r][0] = a.x; qreg[r][1] = a.y; qreg[r][2] = a.z; qreg[r][3] = a.w;
        qreg[r][4] = b.x; qreg[r][5] = b.y; qreg[r][6] = b.z; qreg[r][7] = b.w;
    }

    float acc[4][4] = {{0.f}};
    float zacc[4] = {0.f, 0.f, 0.f, 0.f};

    for (int kt = 0; kt < SS; kt += 64) {
        __syncthreads();   // previous GEMM done before overwriting kms/vtile
        {
            int r = tid >> 2;
            int d = (tid & 3) << 1;
            float2 kv2 = *reinterpret_cast<const float2*>(&kmb[(size_t)(kt + r) * NQQ + d]);
            kms[r][d] = kv2.x; kms[r][d + 1] = kv2.y;
        }
        #pragma unroll
        for (int it = 0; it < 4; ++it) {
            int idx = tid + it * 256;
            int r = idx >> 4;
            int cc4 = (idx & 15) << 2;
            *reinterpret_cast<float4*>(&vtile[r][cc4]) =
                *reinterpret_cast<const float4*>(&Vb[(size_t)(kt + r) * DKK + cc4]);
        }
        __syncthreads();

        // sim + exp -> w tile, plus row-sum partials
        float wv[4][4];
        #pragma unroll
        for (int cc = 0; cc < 4; ++cc) {
            int kk = 4 * tx + cc;
            float s0 = 0.f, s1 = 0.f, s2 = 0.f, s3 = 0.f;
            #pragma unroll
            for (int d = 0; d < 8; ++d) {
                float kvv = kms[kk][d];
                s0 += qreg[0][d] * kvv; s1 += qreg[1][d] * kvv;
                s2 += qreg[2][d] * kvv; s3 += qreg[3][d] * kvv;
            }
            wv[0][cc] = __expf(s0); wv[1][cc] = __expf(s1);
            wv[2][cc] = __expf(s2); wv[3][cc] = __expf(s3);
        }
        #pragma unroll
        for (int r = 0; r < 4; ++r) {
            zacc[r] += wv[r][0] + wv[r][1] + wv[r][2] + wv[r][3];
            float4 w4;
            w4.x = wv[r][0]; w4.y = wv[r][1]; w4.z = wv[r][2]; w4.w = wv[r][3];
            *reinterpret_cast<float4*>(&wsh[4 * ty + r][4 * tx]) = w4;
        }
        __syncthreads();

        // acc += w[64q][64k] @ vtile[64k][64dk]
        #pragma unroll 4
        for (int kg = 0; kg < 16; ++kg) {
            float wr[4][4], vr[4][4];
            #pragma unroll
            for (int r = 0; r < 4; ++r) {
                float4 t = *reinterpret_cast<const float4*>(&wsh[4 * ty + r][4 * kg]);
                wr[r][0] = t.x; wr[r][1] = t.y; wr[r][2] = t.z; wr[r][3] = t.w;
            }
            #pragma unroll
            for (int j = 0; j < 4; ++j) {
                float4 t = *reinterpret_cast<const float4*>(&vtile[4 * kg + j][4 * tx]);
                vr[j][0] = t.x; vr[j][1] = t.y; vr[j][2] = t.z; vr[j][3] = t.w;
            }
            #pragma unroll
            for (int r = 0; r < 4; ++r)
                #pragma unroll
                for (int j = 0; j < 4; ++j)
                    #pragma unroll
                    for (int c = 0; c < 4; ++c)
                        acc[r][c] += wr[r][j] * vr[j][c];
        }
    }

    // reduce Z across the 16 tx-slices per q-row
    __syncthreads();
    #pragma unroll
    for (int r = 0; r < 4; ++r) zred[tx][4 * ty + r] = zacc[r];
    __syncthreads();
    if (tid < 64) {
        float z = 0.f;
        #pragma unroll
        for (int t = 0; t < 16; ++t) z += zred[t][tid];
        zinv[tid] = 1.0f / z;
    }
    __syncthreads();

    const int b = bh >> 3, h = bh & 7;
    #pragma unroll
    for (int r = 0; r < 4; ++r) {
        int s = q0 + 4 * ty + r;
        float zi = zinv[4 * ty + r];
        float4 o;
        o.x = acc[r][0] * zi; o.y = acc[r][1] * zi;
        o.z = acc[r][2] * zi; o.w = acc[r][3] * zi;
        *reinterpret_cast<float4*>(
            &att[(((size_t)b * SS + s) * EE) + h * DKK + 4 * tx]) = o;
    }
}

// ---------------------------------------------------------------------------
extern "C" void kernel_launch(void* const* d_in, const int* in_sizes, int n_in,
                              void* d_out, int out_size, void* d_ws, size_t ws_size,
                              hipStream_t stream)
{
    const float* x  = (const float*)d_in[0];
    const float* Wq = (const float*)d_in[1];
    const float* bq = (const float*)d_in[2];
    const float* Wk = (const float*)d_in[3];
    const float* bk = (const float*)d_in[4];
    const float* Wv = (const float*)d_in[5];
    const float* bv = (const float*)d_in[6];
    const float* Wo = (const float*)d_in[7];
    const float* bo = (const float*)d_in[8];
    // d_in[9] = kernel_params: unused (quantum circuit collapses to cos())

    float* ws = (float*)d_ws;
    float* qm  = ws;                              // B*H*S*NQ = 524288
    float* km  = qm + (size_t)BB * HH * SS * NQQ; // 524288
    float* V   = km + (size_t)BB * HH * SS * NQQ; // B*H*S*DK = 4194304
    float* att = V  + (size_t)BB * HH * SS * DKK; // B*S*E    = 4194304
    float* out = (float*)d_out;

    // A: fused Q/K projection + cos  (only 64 live columns each)
    qk_proj_kernel<<<dim3(BS / 64), 256, 0, stream>>>(x, Wq, bq, Wk, bk, qm, km);
    // B: V projection -> [B,H,S,DK]
    gemm_bias_kernel<1><<<dim3(BS / 64, EE / 64), 256, 0, stream>>>(x, Wv, bv, V);
    // C: attention -> [B,S,E] (head-merged)
    attn_kernel<<<dim3(SS / 64, BB * HH), 256, 0, stream>>>(qm, km, V, att);
    // D: output projection + bias
    gemm_bias_kernel<0><<<dim3(BS / 64, EE / 64), 256, 0, stream>>>(att, Wo, bo, out);
}

// Round 2
// 295.213 us; speedup vs baseline: 1.6479x; 1.6479x over previous
//
#include <hip/hip_runtime.h>
#include <hip/hip_bf16.h>

// Problem constants
#define BB 4
#define SS 2048
#define EE 512
#define HH 8
#define DKK 64
#define NQQ 8
#define BS (BB * SS)   // 8192 rows

typedef __attribute__((ext_vector_type(8))) short bf16x8;
typedef __attribute__((ext_vector_type(4))) float f32x4;

__device__ __forceinline__ unsigned short f2bf(float f) {
    union { float f; unsigned u; } v; v.f = f;
    unsigned r = v.u + 0x7fffu + ((v.u >> 16) & 1u);   // RNE
    return (unsigned short)(r >> 16);
}

// ---------------------------------------------------------------------------
// Kernel A: fused Q/K projection + cos (only 64 live cols each). Unchanged.
// ---------------------------------------------------------------------------
__global__ __launch_bounds__(256) void qk_proj_kernel(
    const float* __restrict__ x,
    const float* __restrict__ Wq, const float* __restrict__ bq,
    const float* __restrict__ Wk, const float* __restrict__ bk,
    float* __restrict__ qm, float* __restrict__ km)
{
    __shared__ float xs[64][36];
    __shared__ float wqs[32][64];
    __shared__ float wks[32][64];

    const int tid = threadIdx.x;
    const int tx = tid & 15, ty = tid >> 4;
    const int row0 = blockIdx.x * 64;
    const int c4 = 4 * tx;
    const int wcol = ((c4 >> 3) << 6) | (c4 & 7);

    float accq[4][4] = {{0.f}};
    float acck[4][4] = {{0.f}};

    for (int k0 = 0; k0 < EE; k0 += 32) {
        __syncthreads();
        #pragma unroll
        for (int it = 0; it < 2; ++it) {
            int idx = tid + it * 256;
            int r = idx >> 3;
            int kk = (idx & 7) << 2;
            *reinterpret_cast<float4*>(&xs[r][kk]) =
                *reinterpret_cast<const float4*>(&x[(size_t)(row0 + r) * EE + k0 + kk]);
        }
        #pragma unroll
        for (int it = 0; it < 2; ++it) {
            int idx = tid + it * 256;
            int kk = idx >> 4;
            int cc4 = (idx & 15) << 2;
            int wc = ((cc4 >> 3) << 6) | (cc4 & 7);
            *reinterpret_cast<float4*>(&wqs[kk][cc4]) =
                *reinterpret_cast<const float4*>(&Wq[(size_t)(k0 + kk) * EE + wc]);
            *reinterpret_cast<float4*>(&wks[kk][cc4]) =
                *reinterpret_cast<const float4*>(&Wk[(size_t)(k0 + kk) * EE + wc]);
        }
        __syncthreads();
        #pragma unroll 8
        for (int k = 0; k < 32; ++k) {
            float a[4];
            #pragma unroll
            for (int r = 0; r < 4; ++r) a[r] = xs[4 * ty + r][k];
            float4 qv = *reinterpret_cast<const float4*>(&wqs[k][c4]);
            float4 kv = *reinterpret_cast<const float4*>(&wks[k][c4]);
            #pragma unroll
            for (int r = 0; r < 4; ++r) {
                accq[r][0] += a[r] * qv.x; accq[r][1] += a[r] * qv.y;
                accq[r][2] += a[r] * qv.z; accq[r][3] += a[r] * qv.w;
                acck[r][0] += a[r] * kv.x; acck[r][1] += a[r] * kv.y;
                acck[r][2] += a[r] * kv.z; acck[r][3] += a[r] * kv.w;
            }
        }
    }

    const int h = c4 >> 3;
    const int j0 = c4 & 7;
    const float4 bqv = *reinterpret_cast<const float4*>(&bq[wcol]);
    const float4 bkv = *reinterpret_cast<const float4*>(&bk[wcol]);
    #pragma unroll
    for (int r = 0; r < 4; ++r) {
        int row = row0 + 4 * ty + r;
        int b = row >> 11;
        int s = row & 2047;
        size_t base = (((size_t)(b * HH + h)) * SS + s) * NQQ + j0;
        float4 oq, ok;
        oq.x = __cosf(accq[r][0] + bqv.x); oq.y = __cosf(accq[r][1] + bqv.y);
        oq.z = __cosf(accq[r][2] + bqv.z); oq.w = __cosf(accq[r][3] + bqv.w);
        ok.x = __cosf(acck[r][0] + bkv.x); ok.y = __cosf(acck[r][1] + bkv.y);
        ok.z = __cosf(acck[r][2] + bkv.z); ok.w = __cosf(acck[r][3] + bkv.w);
        *reinterpret_cast<float4*>(&qm[base]) = oq;
        *reinterpret_cast<float4*>(&km[base]) = ok;
    }
}

// ---------------------------------------------------------------------------
// Kernel B/D: fp32 GEMM + bias. Unchanged.
// ---------------------------------------------------------------------------
template<int VLAYOUT>
__global__ __launch_bounds__(256) void gemm_bias_kernel(
    const float* __restrict__ A, const float* __restrict__ W,
    const float* __restrict__ bias, float* __restrict__ out)
{
    __shared__ float xs[64][36];
    __shared__ float wst[32][64];

    const int tid = threadIdx.x;
    const int tx = tid & 15, ty = tid >> 4;
    const int row0 = blockIdx.x * 64;
    const int col0 = blockIdx.y * 64;

    float acc[4][4] = {{0.f}};

    for (int k0 = 0; k0 < EE; k0 += 32) {
        __syncthreads();
        #pragma unroll
        for (int it = 0; it < 2; ++it) {
            int idx = tid + it * 256;
            int r = idx >> 3;
            int kk = (idx & 7) << 2;
            *reinterpret_cast<float4*>(&xs[r][kk]) =
                *reinterpret_cast<const float4*>(&A[(size_t)(row0 + r) * EE + k0 + kk]);
        }
        #pragma unroll
        for (int it = 0; it < 2; ++it) {
            int idx = tid + it * 256;
            int kk = idx >> 4;
            int cc4 = (idx & 15) << 2;
            *reinterpret_cast<float4*>(&wst[kk][cc4]) =
                *reinterpret_cast<const float4*>(&W[(size_t)(k0 + kk) * EE + col0 + cc4]);
        }
        __syncthreads();
        #pragma unroll 8
        for (int k = 0; k < 32; ++k) {
            float a[4];
            #pragma unroll
            for (int r = 0; r < 4; ++r) a[r] = xs[4 * ty + r][k];
            float4 wv = *reinterpret_cast<const float4*>(&wst[k][4 * tx]);
            #pragma unroll
            for (int r = 0; r < 4; ++r) {
                acc[r][0] += a[r] * wv.x; acc[r][1] += a[r] * wv.y;
                acc[r][2] += a[r] * wv.z; acc[r][3] += a[r] * wv.w;
            }
        }
    }

    const float4 bv = *reinterpret_cast<const float4*>(&bias[col0 + 4 * tx]);
    #pragma unroll
    for (int r = 0; r < 4; ++r) {
        int row = row0 + 4 * ty + r;
        float4 o;
        o.x = acc[r][0] + bv.x; o.y = acc[r][1] + bv.y;
        o.z = acc[r][2] + bv.z; o.w = acc[r][3] + bv.w;
        if (VLAYOUT) {
            int b = row >> 11;
            int s = row & 2047;
            int h = col0 >> 6;
            size_t off = (((size_t)(b * HH + h)) * SS + s) * DKK + 4 * tx;
            *reinterpret_cast<float4*>(&out[off]) = o;
        } else {
            *reinterpret_cast<float4*>(&out[(size_t)row * EE + col0 + 4 * tx]) = o;
        }
    }
}

// ---------------------------------------------------------------------------
// Kernel C v2: attention with bf16-MFMA PV.
// Block: one (b,h) x 128 q-rows, 4 waves (wave = 32 q-rows), k-tiles of 64.
// Per lane: sim q-row == A-frag row (lane&15), k slots == 8*(lane>>4)+j,
// so w=exp(sim) is computed directly in A-fragment layout (no LDS for w).
// V staged to LDS as bf16 [64][76] (<=2-way banks); km fp32 [64][10].
// A-frag:  A[m=l&15][k=8*(l>>4)+j]      (CDNA standard, K-contiguous regs)
// B-frag:  B[k=8*(l>>4)+j][n=l&15]
// C-frag:  C[row=(l>>4)*4+r][col=l&15]  (m89-verified)
// ---------------------------------------------------------------------------
__global__ __launch_bounds__(256) void attn_mfma_kernel(
    const float* __restrict__ qm, const float* __restrict__ km,
    const float* __restrict__ V, float* __restrict__ att)
{
    __shared__ unsigned short vt[64][76];   // bf16 V tile, stride 76
    __shared__ float kml[64][10];           // fp32 km tile, stride 10

    const int tid = threadIdx.x;
    const int lane = tid & 63;
    const int wv = tid >> 6;        // wave 0..3
    const int tx = lane & 15;
    const int tyq = lane >> 4;      // 0..3

    // XCD-aware swizzle: all 16 q-blocks of a (b,h) land on the same XCD
    const int bid = blockIdx.x;
    const int xcd = bid & 7;
    const int sub = bid >> 3;               // 0..63
    const int bh = (xcd << 2) | (sub >> 4); // 0..31
    const int q0 = (sub & 15) * 128;

    const float* __restrict__ qmb = qm + (size_t)bh * SS * NQQ;
    const float* __restrict__ kmb = km + (size_t)bh * SS * NQQ;
    const float* __restrict__ Vb  = V  + (size_t)bh * SS * DKK;

    // q-rows for this lane's two A-tiles (loop-invariant)
    float qreg[2][8];
    #pragma unroll
    for (int qt = 0; qt < 2; ++qt) {
        const float* qp = &qmb[(size_t)(q0 + wv * 32 + qt * 16 + tx) * NQQ];
        float4 a = *reinterpret_cast<const float4*>(qp);
        float4 b = *reinterpret_cast<const float4*>(qp + 4);
        qreg[qt][0] = a.x; qreg[qt][1] = a.y; qreg[qt][2] = a.z; qreg[qt][3] = a.w;
        qreg[qt][4] = b.x; qreg[qt][5] = b.y; qreg[qt][6] = b.z; qreg[qt][7] = b.w;
    }

    f32x4 acc0[4], acc1[4];
    #pragma unroll
    for (int dt = 0; dt < 4; ++dt) {
        acc0[dt] = (f32x4)(0.f);
        acc1[dt] = (f32x4)(0.f);
    }
    float z0 = 0.f, z1 = 0.f;

    for (int kt = 0; kt < SS; kt += 64) {
        __syncthreads();
        // stage km: 64 rows x 8 f32 (2KB contiguous)
        if (tid < 128) {
            int r = tid >> 1, hh = tid & 1;
            float4 t = *reinterpret_cast<const float4*>(&kmb[(size_t)(kt + r) * NQQ + hh * 4]);
            float2* p = reinterpret_cast<float2*>(&kml[r][hh * 4]);
            p[0] = make_float2(t.x, t.y);
            p[1] = make_float2(t.z, t.w);
        }
        // stage V tile -> bf16
        #pragma unroll
        for (int it = 0; it < 4; ++it) {
            int idx = tid + it * 256;
            int row = idx >> 4, c0 = (idx & 15) << 2;
            float4 t = *reinterpret_cast<const float4*>(&Vb[(size_t)(kt + row) * DKK + c0]);
            uint2 p;
            p.x = (unsigned)f2bf(t.x) | ((unsigned)f2bf(t.y) << 16);
            p.y = (unsigned)f2bf(t.z) | ((unsigned)f2bf(t.w) << 16);
            *reinterpret_cast<uint2*>(&vt[row][c0]) = p;
        }
        __syncthreads();

        #pragma unroll
        for (int kb = 0; kb < 2; ++kb) {
            const int kr0 = kb * 32 + tyq * 8;
            // sim + exp for this lane's 8 k's per qt (A-frag layout)
            float w0[8], w1[8];
            #pragma unroll
            for (int j = 0; j < 8; ++j) {
                const float* kr = &kml[kr0 + j][0];
                float2 p0 = *reinterpret_cast<const float2*>(kr + 0);
                float2 p1 = *reinterpret_cast<const float2*>(kr + 2);
                float2 p2 = *reinterpret_cast<const float2*>(kr + 4);
                float2 p3 = *reinterpret_cast<const float2*>(kr + 6);
                float s0 = qreg[0][0] * p0.x + qreg[0][1] * p0.y
                         + qreg[0][2] * p1.x + qreg[0][3] * p1.y
                         + qreg[0][4] * p2.x + qreg[0][5] * p2.y
                         + qreg[0][6] * p3.x + qreg[0][7] * p3.y;
                float s1 = qreg[1][0] * p0.x + qreg[1][1] * p0.y
                         + qreg[1][2] * p1.x + qreg[1][3] * p1.y
                         + qreg[1][4] * p2.x + qreg[1][5] * p2.y
                         + qreg[1][6] * p3.x + qreg[1][7] * p3.y;
                w0[j] = __expf(s0);   // sim in [-8,8]: no max-subtraction needed
                w1[j] = __expf(s1);
            }
            z0 += (w0[0] + w0[1] + w0[2] + w0[3]) + (w0[4] + w0[5] + w0[6] + w0[7]);
            z1 += (w1[0] + w1[1] + w1[2] + w1[3]) + (w1[4] + w1[5] + w1[6] + w1[7]);

            bf16x8 af0, af1;
            #pragma unroll
            for (int j = 0; j < 8; ++j) {
                af0[j] = (short)f2bf(w0[j]);
                af1[j] = (short)f2bf(w1[j]);
            }

            const unsigned short* vp = &vt[kr0][tx];
            #pragma unroll
            for (int dt = 0; dt < 4; ++dt) {
                const unsigned short* vq = vp + dt * 16;
                bf16x8 bf;
                bf[0] = (short)vq[0* 76]; bf[1] = (short)vq[1 * 76];
                bf[2] = (short)vq[2 * 76]; bf[3] = (short)vq[3 * 76];
                bf[4] = (short)vq[4 * 76]; bf[5] = (short)vq[5 * 76];
                bf[6] = (short)vq[6 * 76]; bf[7] = (short)vq[7 * 76];
                acc0[dt] = __builtin_amdgcn_mfma_f32_16x16x32_bf16(af0, bf, acc0[dt], 0, 0, 0);
                acc1[dt] = __builtin_amdgcn_mfma_f32_16x16x32_bf16(af1, bf, acc1[dt], 0, 0, 0);
            }
        }
    }

    // Z: sum the 4 tyq-groups (lanes tx, tx+16, tx+32, tx+48 hold partials of q-row tx)
    z0 += __shfl_xor(z0, 16, 64); z0 += __shfl_xor(z0, 32, 64);
    z1 += __shfl_xor(z1, 16, 64); z1 += __shfl_xor(z1, 32, 64);

    const int b = bh >> 3, h = bh & 7;
    #pragma unroll
    for (int r = 0; r < 4; ++r) {
        int rr = tyq * 4 + r;                    // C-frag row within 16x16 tile
        float zi0 = 1.0f / __shfl(z0, rr, 16);   // Z of q-row rr lives in lane (seg|rr)
        float zi1 = 1.0f / __shfl(z1, rr, 16);
        size_t base0 = ((size_t)b * SS + q0 + wv * 32 + rr) * EE + h * DKK + tx;
        size_t base1 = base0 + (size_t)16 * EE;  // qt=1 is 16 rows down
        #pragma unroll
        for (int dt = 0; dt < 4; ++dt) {
            att[base0 + dt * 16] = acc0[dt][r] * zi0;
            att[base1 + dt * 16] = acc1[dt][r] * zi1;
        }
    }
}

// ---------------------------------------------------------------------------
extern "C" void kernel_launch(void* const* d_in, const int* in_sizes, int n_in,
                              void* d_out, int out_size, void* d_ws, size_t ws_size,
                              hipStream_t stream)
{
    const float* x  = (const float*)d_in[0];
    const float* Wq = (const float*)d_in[1];
    const float* bq = (const float*)d_in[2];
    const float* Wk = (const float*)d_in[3];
    const float* bk = (const float*)d_in[4];
    const float* Wv = (const float*)d_in[5];
    const float* bv = (const float*)d_in[6];
    const float* Wo = (const float*)d_in[7];
    const float* bo = (const float*)d_in[8];
    // d_in[9] = kernel_params: unused (quantum circuit collapses to cos())

    float* ws = (float*)d_ws;
    float* qm  = ws;                              // B*H*S*NQ = 524288
    float* km  = qm + (size_t)BB * HH * SS * NQQ; // 524288
    float* V   = km + (size_t)BB * HH * SS * NQQ; // B*H*S*DK = 4194304
    float* att = V  + (size_t)BB * HH * SS * DKK; // B*S*E    = 4194304
    float* out = (float*)d_out;

    // A: fused Q/K projection + cos
    qk_proj_kernel<<<dim3(BS / 64), 256, 0, stream>>>(x, Wq, bq, Wk, bk, qm, km);
    // B: V projection -> [B,H,S,DK]
    gemm_bias_kernel<1><<<dim3(BS / 64, EE / 64), 256, 0, stream>>>(x, Wv, bv, V);
    // C: attention (bf16-MFMA PV) -> [B,S,E]
    attn_mfma_kernel<<<dim3(512), 256, 0, stream>>>(qm, km, V, att);
    // D: output projection + bias
    gemm_bias_kernel<0><<<dim3(BS / 64, EE / 64), 256, 0, stream>>>(att, Wo, bo, out);
}

// Round 3
// 163.446 us; speedup vs baseline: 2.9764x; 1.8062x over previous
//
#include <hip/hip_runtime.h>
#include <hip/hip_bf16.h>

// Problem constants
#define BB 4
#define SS 2048
#define EE 512
#define HH 8
#define DKK 64
#define NQQ 8
#define BS (BB * SS)   // 8192 rows

typedef __attribute__((ext_vector_type(8))) short bf16x8;
typedef __attribute__((ext_vector_type(4))) float f32x4;
typedef unsigned short u16;
typedef unsigned int u32;

__device__ __forceinline__ u16 f2bf(float f) {
    union { float f; u32 u; } v; v.f = f;
    u32 r = v.u + 0x7fffu + ((v.u >> 16) & 1u);   // RNE
    return (u16)(r >> 16);
}

// ---------------------------------------------------------------------------
// P1: fp32 -> bf16 elementwise (x -> xb). 16B in / 8B out per thread.
// ---------------------------------------------------------------------------
__global__ __launch_bounds__(256) void cvt_bf16_kernel(
    const float4* __restrict__ in, uint2* __restrict__ out, int n4)
{
    int i = blockIdx.x * 256 + threadIdx.x;
    if (i >= n4) return;
    float4 a = in[i];
    out[i] = make_uint2((u32)f2bf(a.x) | ((u32)f2bf(a.y) << 16),
                        (u32)f2bf(a.z) | ((u32)f2bf(a.w) << 16));
}

// ---------------------------------------------------------------------------
// P2: W [512][512] f32 -> WT [512][512] bf16, WT[n][k] = W[k][n].
// 64x64 tile per block via LDS (pad 65 -> conflict-free column reads).
// ---------------------------------------------------------------------------
__global__ __launch_bounds__(256) void wtrans_kernel(
    const float* __restrict__ W, u16* __restrict__ WT)
{
    __shared__ float ts[64][65];
    const int kt0 = blockIdx.x * 64, nt0 = blockIdx.y * 64;
    const int tid = threadIdx.x;
    #pragma unroll
    for (int i = 0; i < 4; ++i) {
        int c = tid + i * 256;
        int kr = c >> 4, nc = (c & 15) * 4;
        float4 t = *reinterpret_cast<const float4*>(&W[(size_t)(kt0 + kr) * EE + nt0 + nc]);
        ts[kr][nc] = t.x; ts[kr][nc + 1] = t.y; ts[kr][nc + 2] = t.z; ts[kr][nc + 3] = t.w;
    }
    __syncthreads();
    const int n = tid >> 2, k0 = (tid & 3) * 16;
    u32 o[8];
    #pragma unroll
    for (int j = 0; j < 8; ++j) {
        o[j] = (u32)f2bf(ts[k0 + 2 * j][n]) | ((u32)f2bf(ts[k0 + 2 * j + 1][n]) << 16);
    }
    uint4* dst = reinterpret_cast<uint4*>(&WT[(size_t)(nt0 + n) * EE + kt0 + k0]);
    dst[0] = make_uint4(o[0], o[1], o[2], o[3]);
    dst[1] = make_uint4(o[4], o[5], o[6], o[7]);
}

// ---------------------------------------------------------------------------
// Kernel A: fused Q/K projection + cos (only 64 live cols each). Unchanged.
// ---------------------------------------------------------------------------
__global__ __launch_bounds__(256) void qk_proj_kernel(
    const float* __restrict__ x,
    const float* __restrict__ Wq, const float* __restrict__ bq,
    const float* __restrict__ Wk, const float* __restrict__ bk,
    float* __restrict__ qm, float* __restrict__ km)
{
    __shared__ float xs[64][36];
    __shared__ float wqs[32][64];
    __shared__ float wks[32][64];

    const int tid = threadIdx.x;
    const int tx = tid & 15, ty = tid >> 4;
    const int row0 = blockIdx.x * 64;
    const int c4 = 4 * tx;
    const int wcol = ((c4 >> 3) << 6) | (c4 & 7);

    float accq[4][4] = {{0.f}};
    float acck[4][4] = {{0.f}};

    for (int k0 = 0; k0 < EE; k0 += 32) {
        __syncthreads();
        #pragma unroll
        for (int it = 0; it < 2; ++it) {
            int idx = tid + it * 256;
            int r = idx >> 3;
            int kk = (idx & 7) << 2;
            *reinterpret_cast<float4*>(&xs[r][kk]) =
                *reinterpret_cast<const float4*>(&x[(size_t)(row0 + r) * EE + k0 + kk]);
        }
        #pragma unroll
        for (int it = 0; it < 2; ++it) {
            int idx = tid + it * 256;
            int kk = idx >> 4;
            int cc4 = (idx & 15) << 2;
            int wc = ((cc4 >> 3) << 6) | (cc4 & 7);
            *reinterpret_cast<float4*>(&wqs[kk][cc4]) =
                *reinterpret_cast<const float4*>(&Wq[(size_t)(k0 + kk) * EE + wc]);
            *reinterpret_cast<float4*>(&wks[kk][cc4]) =
                *reinterpret_cast<const float4*>(&Wk[(size_t)(k0 + kk) * EE + wc]);
        }
        __syncthreads();
        #pragma unroll 8
        for (int k = 0; k < 32; ++k) {
            float a[4];
            #pragma unroll
            for (int r = 0; r < 4; ++r) a[r] = xs[4 * ty + r][k];
            float4 qv = *reinterpret_cast<const float4*>(&wqs[k][c4]);
            float4 kv = *reinterpret_cast<const float4*>(&wks[k][c4]);
            #pragma unroll
            for (int r = 0; r < 4; ++r) {
                accq[r][0] += a[r] * qv.x; accq[r][1] += a[r] * qv.y;
                accq[r][2] += a[r] * qv.z; accq[r][3] += a[r] * qv.w;
                acck[r][0] += a[r] * kv.x; acck[r][1] += a[r] * kv.y;
                acck[r][2] += a[r] * kv.z; acck[r][3] += a[r] * kv.w;
            }
        }
    }

    const int h = c4 >> 3;
    const int j0 = c4 & 7;
    const float4 bqv = *reinterpret_cast<const float4*>(&bq[wcol]);
    const float4 bkv = *reinterpret_cast<const float4*>(&bk[wcol]);
    #pragma unroll
    for (int r = 0; r < 4; ++r) {
        int row = row0 + 4 * ty + r;
        int b = row >> 11;
        int s = row & 2047;
        size_t base = (((size_t)(b * HH + h)) * SS + s) * NQQ + j0;
        float4 oq, ok;
        oq.x = __cosf(accq[r][0] + bqv.x); oq.y = __cosf(accq[r][1] + bqv.y);
        oq.z = __cosf(accq[r][2] + bqv.z); oq.w = __cosf(accq[r][3] + bqv.w);
        ok.x = __cosf(acck[r][0] + bkv.x); ok.y = __cosf(acck[r][1] + bkv.y);
        ok.z = __cosf(acck[r][2] + bkv.z); ok.w = __cosf(acck[r][3] + bkv.w);
        *reinterpret_cast<float4*>(&qm[base]) = oq;
        *reinterpret_cast<float4*>(&km[base]) = ok;
    }
}

// ---------------------------------------------------------------------------
// bf16 MFMA GEMM: out[m][n] = sum_k A[m][k] * Bm[n][k]  (+ bias)
// A, Bm row-major [*,512] bf16. 64x64 tile, 256 thr (2x2 waves, wave 32x32),
// K-step 64, reg-prefetch staging, 16B-block XOR-swizzled LDS (blk ^= row&7).
// MODE 0: out fp32 [8192][512], bias[n] (out-proj).
// MODE 1: out bf16 VT[b][h][d][s]: m = h*64+d, n = b*2048+s, bias[m] (V-proj^T).
// ---------------------------------------------------------------------------
template<int MODE>
__global__ __launch_bounds__(256) void mfma_gemm_kernel(
    const u16* __restrict__ A, const u16* __restrict__ Bm,
    const float* __restrict__ bias, float* __restrict__ outf, u16* __restrict__ outb)
{
    __shared__ u16 Asl[64 * 64];
    __shared__ u16 Bsl[64 * 64];

    const int tid = threadIdx.x;
    const int lane = tid & 63;
    const int ww = tid >> 6;
    const int wr = ww >> 1, wc = ww & 1;
    const int tx = lane & 15, tyq = lane >> 4;
    const int m0 = blockIdx.x * 64, n0 = blockIdx.y * 64;

    const int c0 = tid, c1 = tid + 256;
    const int r0 = c0 >> 3, o0 = (c0 & 7) * 8, d0 = r0 * 64 + (((c0 & 7) ^ (r0 & 7)) * 8);
    const int r1 = c1 >> 3, o1 = (c1 & 7) * 8, d1 = r1 * 64 + (((c1 & 7) ^ (r1 & 7)) * 8);

    uint4 pa0, pa1, pb0, pb1;
    auto ld = [&](int ks) {
        int k0 = ks * 64;
        pa0 = *reinterpret_cast<const uint4*>(&A [(size_t)(m0 + r0) * EE + k0 + o0]);
        pb0 = *reinterpret_cast<const uint4*>(&Bm[(size_t)(n0 + r0) * EE + k0 + o0]);
        pa1 = *reinterpret_cast<const uint4*>(&A [(size_t)(m0 + r1) * EE + k0 + o1]);
        pb1 = *reinterpret_cast<const uint4*>(&Bm[(size_t)(n0 + r1) * EE + k0 + o1]);
    };
    auto st = [&]() {
        *reinterpret_cast<uint4*>(&Asl[d0]) = pa0;
        *reinterpret_cast<uint4*>(&Bsl[d0]) = pb0;
        *reinterpret_cast<uint4*>(&Asl[d1]) = pa1;
        *reinterpret_cast<uint4*>(&Bsl[d1]) = pb1;
    };

    f32x4 acc[2][2];
    #pragma unroll
    for (int mt = 0; mt < 2; ++mt)
        #pragma unroll
        for (int nt = 0; nt < 2; ++nt) acc[mt][nt] = (f32x4)(0.f);

    const int bkx = tx & 7;
    ld(0);
    for (int ks = 0; ks < 8; ++ks) {
        __syncthreads();
        st();
        if (ks < 7) ld(ks + 1);
        __syncthreads();
        #pragma unroll
        for (int kb = 0; kb < 2; ++kb) {
            bf16x8 af[2], bfg[2];
            const int kblk = ((kb * 4 + tyq) ^ bkx) * 8;
            #pragma unroll
            for (int mt = 0; mt < 2; ++mt) {
                int row = wr * 32 + mt * 16 + tx;
                af[mt] = *reinterpret_cast<const bf16x8*>(&Asl[row * 64 + kblk]);
            }
            #pragma unroll
            for (int nt = 0; nt < 2; ++nt) {
                int row = wc * 32 + nt * 16 + tx;
                bfg[nt] = *reinterpret_cast<const bf16x8*>(&Bsl[row * 64 + kblk]);
            }
            #pragma unroll
            for (int mt = 0; mt < 2; ++mt)
                #pragma unroll
                for (int nt = 0; nt < 2; ++nt)
                    acc[mt][nt] = __builtin_amdgcn_mfma_f32_16x16x32_bf16(
                        af[mt], bfg[nt], acc[mt][nt], 0, 0, 0);
        }
    }

    #pragma unroll
    for (int mt = 0; mt < 2; ++mt) {
        #pragma unroll
        for (int nt = 0; nt < 2; ++nt) {
            int gcol = n0 + wc * 32 + nt * 16 + tx;
            float bcol = (MODE == 0) ? bias[gcol] : 0.f;
            #pragma unroll
            for (int r = 0; r < 4; ++r) {
                int grow = m0 + wr * 32 + mt * 16 + tyq * 4 + r;
                float v = acc[mt][nt][r];
                if (MODE == 0) {
                    outf[(size_t)grow * EE + gcol] = v + bcol;
                } else {
                    float vb = v + bias[grow];
                    size_t addr = ((size_t)((gcol >> 11) * 8 + (grow >> 6))) * (64 * 2048)
                                + (size_t)(grow & 63) * 2048 + (gcol & 2047);
                    outb[addr] = f2bf(vb);
                }
            }
        }
    }
}

// ---------------------------------------------------------------------------
// Kernel C v3: attention, bf16-MFMA PV with pre-transposed bf16 V (VT[d][s]).
// Block: one (b,h) x 128 q, 4 waves x 32 q. Per k-tile of 64:
//   sim (fp32 VALU, km broadcast reads) -> exp -> A-frag in-register;
//   B-frag = ONE ds_read_b128 from swizzled VT tile. Output att in bf16.
// ---------------------------------------------------------------------------
__global__ __launch_bounds__(256) void attn_mfma3_kernel(
    const float* __restrict__ qm, const float* __restrict__ km,
    const u16* __restrict__ VT, u16* __restrict__ attb)
{
    __shared__ u16 vtl[64 * 64];     // [d=64][k=64] bf16, 16B-block swizzled
    __shared__ float kml[64][8];     // [k=64][8] f32 (broadcast reads)

    const int tid = threadIdx.x;
    const int lane = tid & 63;
    const int wv = tid >> 6;
    const int tx = lane & 15, tyq = lane >> 4;

    // XCD-aware swizzle: all 16 q-blocks of a (b,h) on one XCD
    const int bid = blockIdx.x;
    const int xcd = bid & 7;
    const int sub = bid >> 3;
    const int bh = (xcd << 2) | (sub >> 4);
    const int q0 = (sub & 15) * 128;

    const float* __restrict__ qmb = qm + (size_t)bh * SS * NQQ;
    const float* __restrict__ kmb = km + (size_t)bh * SS * NQQ;
    const u16* __restrict__ VTb = VT + (size_t)bh * DKK * SS;   // [64][2048]

    float qreg[2][8];
    #pragma unroll
    for (int qt = 0; qt < 2; ++qt) {
        const float* qp = &qmb[(size_t)(q0 + wv * 32 + qt * 16 + tx) * NQQ];
        float4 a = *reinterpret_cast<const float4*>(qp);
        float4 b = *reinterpret_cast<const float4*>(qp + 4);
        qreg[qt][0] = a.x; qreg[qt][1] = a.y; qreg[qt][2] = a.z; qreg[qt][3] = a.w;
        qreg[qt][4] = b.x; qreg[qt][5] = b.y; qreg[qt][6] = b.z; qreg[qt][7] = b.w;
    }

    f32x4 acc0[4], acc1[4];
    #pragma unroll
    for (int dt = 0; dt < 4; ++dt) { acc0[dt] = (f32x4)(0.f); acc1[dt] = (f32x4)(0.f); }
    float z0 = 0.f, z1 = 0.f;

    const int c0 = tid, c1 = tid + 256;
    const int r0 = c0 >> 3, o0 = (c0 & 7) * 8, d0 = r0 * 64 + (((c0 & 7) ^ (r0 & 7)) * 8);
    const int r1 = c1 >> 3, o1 = (c1 & 7) * 8, d1 = r1 * 64 + (((c1 & 7) ^ (r1 & 7)) * 8);
    const int kmr = tid >> 1, kmh = (tid & 1) * 4;

    uint4 pv0, pv1; float4 pk;
    auto ldv = [&](int kt) {
        pv0 = *reinterpret_cast<const uint4*>(&VTb[(size_t)r0 * SS + kt + o0]);
        pv1 = *reinterpret_cast<const uint4*>(&VTb[(size_t)r1 * SS + kt + o1]);
        if (tid < 128)
            pk = *reinterpret_cast<const float4*>(&kmb[(size_t)(kt + kmr) * NQQ + kmh]);
    };
    auto stv = [&]() {
        *reinterpret_cast<uint4*>(&vtl[d0]) = pv0;
        *reinterpret_cast<uint4*>(&vtl[d1]) = pv1;
        if (tid < 128)
            *reinterpret_cast<float4*>(&kml[kmr][kmh]) = pk;
    };

    const int bkx = tx & 7;
    ldv(0);
    for (int kt = 0; kt < SS; kt += 64) {
        __syncthreads();
        stv();
        if (kt + 64 < SS) ldv(kt + 64);
        __syncthreads();

        #pragma unroll
        for (int kb = 0; kb < 2; ++kb) {
            const int kr0 = kb * 32 + tyq * 8;
            float w0[8], w1[8];
            #pragma unroll
            for (int j = 0; j < 8; ++j) {
                const float* kr = &kml[kr0 + j][0];
                float4 pA = *reinterpret_cast<const float4*>(kr);
                float4 pB = *reinterpret_cast<const float4*>(kr + 4);
                float s0 = qreg[0][0] * pA.x + qreg[0][1] * pA.y + qreg[0][2] * pA.z + qreg[0][3] * pA.w
                         + qreg[0][4] * pB.x + qreg[0][5] * pB.y + qreg[0][6] * pB.z + qreg[0][7] * pB.w;
                float s1 = qreg[1][0] * pA.x + qreg[1][1] * pA.y + qreg[1][2] * pA.z + qreg[1][3] * pA.w
                         + qreg[1][4] * pB.x + qreg[1][5] * pB.y + qreg[1][6] * pB.z + qreg[1][7] * pB.w;
                w0[j] = __expf(s0);   // sim in [-8,8]: no max-subtraction needed
                w1[j] = __expf(s1);
            }
            z0 += (w0[0] + w0[1] + w0[2] + w0[3]) + (w0[4] + w0[5] + w0[6] + w0[7]);
            z1 += (w1[0] + w1[1] + w1[2] + w1[3]) + (w1[4] + w1[5] + w1[6] + w1[7]);

            bf16x8 af0, af1;
            #pragma unroll
            for (int j = 0; j < 8; ++j) {
                af0[j] = (short)f2bf(w0[j]);
                af1[j] = (short)f2bf(w1[j]);
            }

            const int kblk = ((kb * 4 + tyq) ^ bkx) * 8;
            #pragma unroll
            for (int dt = 0; dt < 4; ++dt) {
                int row = dt * 16 + tx;
                bf16x8 bfr = *reinterpret_cast<const bf16x8*>(&vtl[row * 64 + kblk]);
                acc0[dt] = __builtin_amdgcn_mfma_f32_16x16x32_bf16(af0, bfr, acc0[dt], 0, 0, 0);
                acc1[dt] = __builtin_amdgcn_mfma_f32_16x16x32_bf16(af1, bfr, acc1[dt], 0, 0, 0);
            }
        }
    }

    // Z: lanes tx, tx+16, tx+32, tx+48 hold partials of q-row tx
    z0 += __shfl_xor(z0, 16, 64); z0 += __shfl_xor(z0, 32, 64);
    z1 += __shfl_xor(z1, 16, 64); z1 += __shfl_xor(z1, 32, 64);

    const int b = bh >> 3, h = bh & 7;
    #pragma unroll
    for (int r = 0; r < 4; ++r) {
        int rr = tyq * 4 + r;                    // C-frag row within 16x16 tile
        float zi0 = 1.0f / __shfl(z0, rr, 16);
        float zi1 = 1.0f / __shfl(z1, rr, 16);
        size_t base0 = ((size_t)b * SS + q0 + wv * 32 + rr) * EE + h * DKK + tx;
        size_t base1 = base0 + (size_t)16 * EE;  // qt=1 is 16 rows down
        #pragma unroll
        for (int dt = 0; dt < 4; ++dt) {
            attb[base0 + dt * 16] = f2bf(acc0[dt][r] * zi0);
            attb[base1 + dt * 16] = f2bf(acc1[dt][r] * zi1);
        }
    }
}

// ---------------------------------------------------------------------------
extern "C" void kernel_launch(void* const* d_in, const int* in_sizes, int n_in,
                              void* d_out, int out_size, void* d_ws, size_t ws_size,
                              hipStream_t stream)
{
    const float* x  = (const float*)d_in[0];
    const float* Wq = (const float*)d_in[1];
    const float* bq = (const float*)d_in[2];
    const float* Wk = (const float*)d_in[3];
    const float* bk = (const float*)d_in[4];
    const float* Wv = (const float*)d_in[5];
    const float* bv = (const float*)d_in[6];
    const float* Wo = (const float*)d_in[7];
    const float* bo = (const float*)d_in[8];
    // d_in[9] = kernel_params: unused (quantum circuit collapses to cos())

    char* w = (char*)d_ws;
    u16* xb    = (u16*)w;   w += (size_t)BS * EE * 2;              // 8 MB
    u16* WvT   = (u16*)w;   w += (size_t)EE * EE * 2;              // 0.5 MB
    u16* WoT   = (u16*)w;   w += (size_t)EE * EE * 2;              // 0.5 MB
    float* qm  = (float*)w; w += (size_t)BB * HH * SS * NQQ * 4;   // 2 MB
    float* km  = (float*)w; w += (size_t)BB * HH * SS * NQQ * 4;   // 2 MB
    u16* VT    = (u16*)w;   w += (size_t)BB * HH * DKK * SS * 2;   // 8 MB
    u16* attb  = (u16*)w;   w += (size_t)BS * EE * 2;              // 8 MB
    float* out = (float*)d_out;

    // P1: x -> bf16
    cvt_bf16_kernel<<<dim3(BS * EE / 4 / 256), 256, 0, stream>>>(
        (const float4*)x, (uint2*)xb, BS * EE / 4);
    // P2: Wv, Wo -> transposed bf16
    wtrans_kernel<<<dim3(8, 8), 256, 0, stream>>>(Wv, WvT);
    wtrans_kernel<<<dim3(8, 8), 256, 0, stream>>>(Wo, WoT);
    // A: fused Q/K projection + cos
    qk_proj_kernel<<<dim3(BS / 64), 256, 0, stream>>>(x, Wq, bq, Wk, bk, qm, km);
    // B: V projection, computed transposed: VT[h*64+d][b*2048+s] (MFMA bf16)
    mfma_gemm_kernel<1><<<dim3(EE / 64, BS / 64), 256, 0, stream>>>(
        WvT, xb, bv, nullptr, VT);
    // C: attention (bf16-MFMA PV, VT-fragment reads) -> attb bf16 [B*S][E]
    attn_mfma3_kernel<<<dim3(512), 256, 0, stream>>>(qm, km, VT, attb);
    // D: output projection + bias (MFMA bf16, fp32 out)
    mfma_gemm_kernel<0><<<dim3(BS / 64, EE / 64), 256, 0, stream>>>(
        attb, WoT, bo, out, nullptr);
}

// Round 4
// 102.587 us; speedup vs baseline: 4.7422x; 1.5932x over previous
//
#include <hip/hip_runtime.h>
#include <hip/hip_bf16.h>

// Problem constants
#define BB 4
#define SS 2048
#define EE 512
#define HH 8
#define DKK 64
#define NQQ 8
#define BS (BB * SS)   // 8192 rows

typedef __attribute__((ext_vector_type(8))) short bf16x8;
typedef __attribute__((ext_vector_type(4))) float f32x4;
typedef _Float16 f16x4 __attribute__((ext_vector_type(4)));
typedef unsigned short u16;
typedef unsigned int u32;

union U2H { uint2 u; f16x4 h; };

__device__ __forceinline__ u16 f2bf(float f) {
    union { float f; u32 u; } v; v.f = f;
    u32 r = v.u + 0x7fffu + ((v.u >> 16) & 1u);   // RNE
    return (u16)(r >> 16);
}
__device__ __forceinline__ float bf2f(u16 h) {
    union { u32 u; float f; } v; v.u = ((u32)h) << 16;
    return v.f;
}
__device__ __forceinline__ u16 f2h(float f) {
    _Float16 hv = (_Float16)f;
    return *reinterpret_cast<u16*>(&hv);
}

// ---------------------------------------------------------------------------
// P1: x fp32 -> xh (bf16) + xl (bf16 residual).  hi/lo split for fp32-grade
// MFMA projections.
// ---------------------------------------------------------------------------
__global__ __launch_bounds__(256) void cvt2_kernel(
    const float4* __restrict__ in, uint2* __restrict__ xh, uint2* __restrict__ xl, int n4)
{
    int i = blockIdx.x * 256 + threadIdx.x;
    if (i >= n4) return;
    float4 a = in[i];
    u16 h0 = f2bf(a.x), h1 = f2bf(a.y), h2 = f2bf(a.z), h3 = f2bf(a.w);
    u16 l0 = f2bf(a.x - bf2f(h0)), l1 = f2bf(a.y - bf2f(h1));
    u16 l2 = f2bf(a.z - bf2f(h2)), l3 = f2bf(a.w - bf2f(h3));
    xh[i] = make_uint2((u32)h0 | ((u32)h1 << 16), (u32)h2 | ((u32)h3 << 16));
    xl[i] = make_uint2((u32)l0 | ((u32)l1 << 16), (u32)l2 | ((u32)l3 << 16));
}

// ---------------------------------------------------------------------------
// P2: pack+transpose the 64 live Q/K weight cols each into Wqk{h,l}[128][512]
// bf16 (n<64 = Wq packed col, n>=64 = Wk). Tiny (256 KB useful), L2-absorbed.
// ---------------------------------------------------------------------------
__global__ __launch_bounds__(256) void wqk_pack_kernel(
    const float* __restrict__ Wq, const float* __restrict__ Wk,
    u16* __restrict__ Wh, u16* __restrict__ Wl)
{
    const int n = blockIdx.x;                  // 0..127
    const int col = (((n & 63) >> 3) << 6) | (n & 7);
    const float* src = (n < 64) ? Wq : Wk;
    for (int k = threadIdx.x; k < EE; k += 256) {
        float v = src[(size_t)k * EE + col];
        u16 h = f2bf(v);
        Wh[(size_t)n * EE + k] = h;
        Wl[(size_t)n * EE + k] = f2bf(v - bf2f(h));
    }
}

// ---------------------------------------------------------------------------
// P3: W [512][512] f32 -> WT [512][512] bf16 transposed (for Wv, Wo).
// ---------------------------------------------------------------------------
__global__ __launch_bounds__(256) void wtrans_kernel(
    const float* __restrict__ W, u16* __restrict__ WT)
{
    __shared__ float ts[64][65];
    const int kt0 = blockIdx.x * 64, nt0 = blockIdx.y * 64;
    const int tid = threadIdx.x;
    #pragma unroll
    for (int i = 0; i < 4; ++i) {
        int c = tid + i * 256;
        int kr = c >> 4, nc = (c & 15) * 4;
        float4 t = *reinterpret_cast<const float4*>(&W[(size_t)(kt0 + kr) * EE + nt0 + nc]);
        ts[kr][nc] = t.x; ts[kr][nc + 1] = t.y; ts[kr][nc + 2] = t.z; ts[kr][nc + 3] = t.w;
    }
    __syncthreads();
    const int n = tid >> 2, k0 = (tid & 3) * 16;
    u32 o[8];
    #pragma unroll
    for (int j = 0; j < 8; ++j) {
        o[j] = (u32)f2bf(ts[k0 + 2 * j][n]) | ((u32)f2bf(ts[k0 + 2 * j + 1][n]) << 16);
    }
    uint4* dst = reinterpret_cast<uint4*>(&WT[(size_t)(nt0 + n) * EE + kt0 + k0]);
    dst[0] = make_uint4(o[0], o[1], o[2], o[3]);
    dst[1] = make_uint4(o[4], o[5], o[6], o[7]);
}

// ---------------------------------------------------------------------------
// QK projection via MFMA, double-bf16 (3 passes: xh*Wh + xl*Wh + xh*Wl).
// Tile 64 rows x 64 packed cols; grid (BS/64, 2): y=0 -> q, y=1 -> k.
// Epilogue: cos(proj + bias) in fp32, store f16 to qf/kf [bh][s][8].
// ---------------------------------------------------------------------------
__global__ __launch_bounds__(256) void qk_mfma_kernel(
    const u16* __restrict__ xh, const u16* __restrict__ xl,
    const u16* __restrict__ Wh, const u16* __restrict__ Wl,
    const float* __restrict__ bq, const float* __restrict__ bk,
    u16* __restrict__ qf, u16* __restrict__ kf)
{
    __shared__ u16 Asl[64 * 64];
    __shared__ u16 Bsl[64 * 64];

    const int tid = threadIdx.x;
    const int lane = tid & 63;
    const int ww = tid >> 6;
    const int wr = ww >> 1, wc = ww & 1;
    const int tx = lane & 15, tyq = lane >> 4;
    const int m0 = blockIdx.x * 64;
    const int isK = blockIdx.y;               // 0=q, 1=k
    const int nbase = isK * 64;               // row base in Wh/Wl

    const int c0 = tid, c1 = tid + 256;
    const int r0 = c0 >> 3, o0 = (c0 & 7) * 8, d0 = r0 * 64 + (((c0 & 7) ^ (r0 & 7)) * 8);
    const int r1 = c1 >> 3, o1 = (c1 & 7) * 8, d1 = r1 * 64 + (((c1 & 7) ^ (r1 & 7)) * 8);

    uint4 pa0, pa1, pb0, pb1;
    auto ldi = [&](int it) {
        int pass = it >> 3, k0 = (it & 7) * 64;
        const u16* Ab = (pass == 1) ? xl : xh;
        const u16* Bb = (pass == 2) ? Wl : Wh;
        pa0 = *reinterpret_cast<const uint4*>(&Ab[(size_t)(m0 + r0) * EE + k0 + o0]);
        pb0 = *reinterpret_cast<const uint4*>(&Bb[(size_t)(nbase + r0) * EE + k0 + o0]);
        pa1 = *reinterpret_cast<const uint4*>(&Ab[(size_t)(m0 + r1) * EE + k0 + o1]);
        pb1 = *reinterpret_cast<const uint4*>(&Bb[(size_t)(nbase + r1) * EE + k0 + o1]);
    };
    auto st = [&]() {
        *reinterpret_cast<uint4*>(&Asl[d0]) = pa0;
        *reinterpret_cast<uint4*>(&Bsl[d0]) = pb0;
        *reinterpret_cast<uint4*>(&Asl[d1]) = pa1;
        *reinterpret_cast<uint4*>(&Bsl[d1]) = pb1;
    };

    f32x4 acc[2][2];
    #pragma unroll
    for (int mt = 0; mt < 2; ++mt)
        #pragma unroll
        for (int nt = 0; nt < 2; ++nt) acc[mt][nt] = (f32x4)(0.f);

    const int bkx = tx & 7;
    ldi(0);
    for (int it = 0; it < 24; ++it) {
        __syncthreads();
        st();
        if (it < 23) ldi(it + 1);
        __syncthreads();
        #pragma unroll
        for (int kb = 0; kb < 2; ++kb) {
            bf16x8 af[2], bfg[2];
            const int kblk = ((kb * 4 + tyq) ^ bkx) * 8;
            #pragma unroll
            for (int mt = 0; mt < 2; ++mt)
                af[mt] = *reinterpret_cast<const bf16x8*>(&Asl[(wr * 32 + mt * 16 + tx) * 64 + kblk]);
            #pragma unroll
            for (int nt = 0; nt < 2; ++nt)
                bfg[nt] = *reinterpret_cast<const bf16x8*>(&Bsl[(wc * 32 + nt * 16 + tx) * 64 + kblk]);
            #pragma unroll
            for (int mt = 0; mt < 2; ++mt)
                #pragma unroll
                for (int nt = 0; nt < 2; ++nt)
                    acc[mt][nt] = __builtin_amdgcn_mfma_f32_16x16x32_bf16(
                        af[mt], bfg[nt], acc[mt][nt], 0, 0, 0);
        }
    }

    const float* bias = isK ? bk : bq;
    u16* dst = isK ? kf : qf;
    #pragma unroll
    for (int mt = 0; mt < 2; ++mt) {
        #pragma unroll
        for (int nt = 0; nt < 2; ++nt) {
            int nl = wc * 32 + nt * 16 + tx;            // packed col 0..63
            int h = nl >> 3, f = nl & 7;
            float bcol = bias[h * 64 + f];
            #pragma unroll
            for (int r = 0; r < 4; ++r) {
                int s = m0 + wr * 32 + mt * 16 + tyq * 4 + r;
                float c = __cosf(acc[mt][nt][r] + bcol);
                size_t bh = (size_t)((s >> 11) * HH + h);
                dst[(bh * SS + (s & 2047)) * 8 + f] = f2h(c);
            }
        }
    }
}

// ---------------------------------------------------------------------------
// bf16 MFMA GEMM: out[m][n] = sum_k A[m][k] * Bm[n][k] (+ bias)
// MODE 0: out fp32 [8192][512], bias[n] (out-proj).
// MODE 1: out f16 VT[b][h][d][s]: m=h*64+d, n=b*2048+s, bias[m] (V-proj^T).
// ---------------------------------------------------------------------------
template<int MODE>
__global__ __launch_bounds__(256) void mfma_gemm_kernel(
    const u16* __restrict__ A, const u16* __restrict__ Bm,
    const float* __restrict__ bias, float* __restrict__ outf, u16* __restrict__ outb)
{
    __shared__ u16 Asl[64 * 64];
    __shared__ u16 Bsl[64 * 64];

    const int tid = threadIdx.x;
    const int lane = tid & 63;
    const int ww = tid >> 6;
    const int wr = ww >> 1, wc = ww & 1;
    const int tx = lane & 15, tyq = lane >> 4;
    const int m0 = blockIdx.x * 64, n0 = blockIdx.y * 64;

    const int c0 = tid, c1 = tid + 256;
    const int r0 = c0 >> 3, o0 = (c0 & 7) * 8, d0 = r0 * 64 + (((c0 & 7) ^ (r0 & 7)) * 8);
    const int r1 = c1 >> 3, o1 = (c1 & 7) * 8, d1 = r1 * 64 + (((c1 & 7) ^ (r1 & 7)) * 8);

    uint4 pa0, pa1, pb0, pb1;
    auto ld = [&](int ks) {
        int k0 = ks * 64;
        pa0 = *reinterpret_cast<const uint4*>(&A [(size_t)(m0 + r0) * EE + k0 + o0]);
        pb0 = *reinterpret_cast<const uint4*>(&Bm[(size_t)(n0 + r0) * EE + k0 + o0]);
        pa1 = *reinterpret_cast<const uint4*>(&A [(size_t)(m0 + r1) * EE + k0 + o1]);
        pb1 = *reinterpret_cast<const uint4*>(&Bm[(size_t)(n0 + r1) * EE + k0 + o1]);
    };
    auto st = [&]() {
        *reinterpret_cast<uint4*>(&Asl[d0]) = pa0;
        *reinterpret_cast<uint4*>(&Bsl[d0]) = pb0;
        *reinterpret_cast<uint4*>(&Asl[d1]) = pa1;
        *reinterpret_cast<uint4*>(&Bsl[d1]) = pb1;
    };

    f32x4 acc[2][2];
    #pragma unroll
    for (int mt = 0; mt < 2; ++mt)
        #pragma unroll
        for (int nt = 0; nt < 2; ++nt) acc[mt][nt] = (f32x4)(0.f);

    const int bkx = tx & 7;
    ld(0);
    for (int ks = 0; ks < 8; ++ks) {
        __syncthreads();
        st();
        if (ks < 7) ld(ks + 1);
        __syncthreads();
        #pragma unroll
        for (int kb = 0; kb < 2; ++kb) {
            bf16x8 af[2], bfg[2];
            const int kblk = ((kb * 4 + tyq) ^ bkx) * 8;
            #pragma unroll
            for (int mt = 0; mt < 2; ++mt)
                af[mt] = *reinterpret_cast<const bf16x8*>(&Asl[(wr * 32 + mt * 16 + tx) * 64 + kblk]);
            #pragma unroll
            for (int nt = 0; nt < 2; ++nt)
                bfg[nt] = *reinterpret_cast<const bf16x8*>(&Bsl[(wc * 32 + nt * 16 + tx) * 64 + kblk]);
            #pragma unroll
            for (int mt = 0; mt < 2; ++mt)
                #pragma unroll
                for (int nt = 0; nt < 2; ++nt)
                    acc[mt][nt] = __builtin_amdgcn_mfma_f32_16x16x32_bf16(
                        af[mt], bfg[nt], acc[mt][nt], 0, 0, 0);
        }
    }

    #pragma unroll
    for (int mt = 0; mt < 2; ++mt) {
        #pragma unroll
        for (int nt = 0; nt < 2; ++nt) {
            int gcol = n0 + wc * 32 + nt * 16 + tx;
            float bcol = (MODE == 0) ? bias[gcol] : 0.f;
            #pragma unroll
            for (int r = 0; r < 4; ++r) {
                int grow = m0 + wr * 32 + mt * 16 + tyq * 4 + r;
                float v = acc[mt][nt][r];
                if (MODE == 0) {
                    outf[(size_t)grow * EE + gcol] = v + bcol;
                } else {
                    float vb = v + bias[grow];
                    size_t addr = ((size_t)((gcol >> 11) * 8 + (grow >> 6))) * (64 * 2048)
                                + (size_t)(grow & 63) * 2048 + (gcol & 2047);
                    outb[addr] = f2h(vb);
                }
            }
        }
    }
}

// ---------------------------------------------------------------------------
// Attention v4: both sim and PV on matrix cores (f16 16x16x16 MFMA).
// Block: one (b,h) x 64 q (4 waves x 16 q); k-tiles of 64 (4 chunks of 16).
// sim = mfma(K_frag, Q_frag): C-frag w[kl=4*tyq+r][q=tx] == PV A-frag
// A[m=q=tx][j=kl=4*tyq+j'] -> exp + f16 cast entirely in-register, no
// cross-lane, no LDS for w. K padded 8->16 by zeroing tyq>=2 fragments.
// vtl: f16 V^T tile [d][k] with 16B-block XOR swizzle; kfl: [k][8] f16.
// ---------------------------------------------------------------------------
__global__ __launch_bounds__(256) void attn_v4_kernel(
    const u16* __restrict__ qf, const u16* __restrict__ kf,
    const u16* __restrict__ VT, u16* __restrict__ attb)
{
    __shared__ u16 vtl[64 * 64];   // f16, [d][k] swizzled, 8 KB
    __shared__ u16 kfl[64 * 8];    // f16, [k][f], 1 KB

    const int tid = threadIdx.x;
    const int lane = tid & 63;
    const int wv = tid >> 6;       // wave 0..3 -> q sub-tile
    const int tx = lane & 15, tyq = lane >> 4;

    // XCD-aware swizzle: all 32 q-blocks of a (b,h) on one XCD
    const int bid = blockIdx.x;
    const int xcd = bid & 7, sub = bid >> 3;         // sub 0..127
    const int bh = (xcd << 2) | (sub >> 5);          // 0..31
    const int q0 = (sub & 31) * 64;

    const u16* __restrict__ qfb = qf + (size_t)bh * SS * 8;
    const u16* __restrict__ kfb = kf + (size_t)bh * SS * 8;
    const u16* __restrict__ VTb = VT + (size_t)bh * DKK * SS;

    // Q B-frag (loop-invariant): B[j=4*tyq+j'][n=tx] = qf[q0+wv*16+tx][f], f=j
    uint4 qv = *reinterpret_cast<const uint4*>(&qfb[(size_t)(q0 + wv * 16 + tx) * 8]);
    U2H qb;
    qb.u.x = (tyq == 0) ? qv.x : (tyq == 1 ? qv.z : 0u);
    qb.u.y = (tyq == 0) ? qv.y : (tyq == 1 ? qv.w : 0u);
    const f16x4 QB = qb.h;

    f32x4 acc[4];
    #pragma unroll
    for (int dt = 0; dt < 4; ++dt) acc[dt] = (f32x4)(0.f);
    float z = 0.f;

    const int c0 = tid, c1 = tid + 256;
    const int r0 = c0 >> 3, b0 = c0 & 7, d0 = r0 * 64 + ((b0 ^ (r0 & 7)) * 8);
    const int r1 = c1 >> 3, b1 = c1 & 7, d1 = r1 * 64 + ((b1 ^ (r1 & 7)) * 8);
    const int krow = tid >> 1, khalf = tid & 1;

    uint4 pv0, pv1; uint2 pk;
    auto ldv = [&](int kt) {
        pv0 = *reinterpret_cast<const uint4*>(&VTb[(size_t)r0 * SS + kt + b0 * 8]);
        pv1 = *reinterpret_cast<const uint4*>(&VTb[(size_t)r1 * SS + kt + b1 * 8]);
        if (tid < 128)
            pk = *reinterpret_cast<const uint2*>(&kfb[(size_t)(kt + krow) * 8 + khalf * 4]);
    };
    auto stv = [&]() {
        *reinterpret_cast<uint4*>(&vtl[d0]) = pv0;
        *reinterpret_cast<uint4*>(&vtl[d1]) = pv1;
        if (tid < 128)
            *reinterpret_cast<uint2*>(&kfl[krow * 8 + khalf * 4]) = pk;
    };

    ldv(0);
    for (int kt = 0; kt < SS; kt += 64) {
        __syncthreads();
        stv();
        if (kt + 64 < SS) ldv(kt + 64);
        __syncthreads();

        #pragma unroll
        for (int c = 0; c < 4; ++c) {
            // K A-frag: A[m=k_row=tx][j=4*tyq+j'] = kf[c*16+tx][f], zero j>=8
            uint2 kvu = *reinterpret_cast<const uint2*>(
                &kfl[(c * 16 + tx) * 8 + (tyq & 1) * 4]);
            U2H ka;
            ka.u.x = (tyq < 2) ? kvu.x : 0u;
            ka.u.y = (tyq < 2) ? kvu.y : 0u;

            f32x4 s = (f32x4)(0.f);
            s = __builtin_amdgcn_mfma_f32_16x16x16f16(ka.h, QB, s, 0, 0, 0);

            // sim in [-8,8]: single-pass softmax, no max subtraction
            float w0 = __expf(s[0]), w1 = __expf(s[1]);
            float w2 = __expf(s[2]), w3 = __expf(s[3]);
            z += (w0 + w1) + (w2 + w3);
            f16x4 PA;
            PA[0] = (_Float16)w0; PA[1] = (_Float16)w1;
            PA[2] = (_Float16)w2; PA[3] = (_Float16)w3;

            #pragma unroll
            for (int dt = 0; dt < 4; ++dt) {
                int row = dt * 16 + tx;
                int blk = (2 * c + (tyq >> 1)) ^ (row & 7);
                f16x4 VB = *reinterpret_cast<const f16x4*>(
                    &vtl[row * 64 + blk * 8 + (tyq & 1) * 4]);
                acc[dt] = __builtin_amdgcn_mfma_f32_16x16x16f16(PA, VB, acc[dt], 0, 0, 0);
            }
        }
    }

    // z partials: lane holds partial for q=tx; reduce across tyq groups
    z += __shfl_xor(z, 16, 64);
    z += __shfl_xor(z, 32, 64);

    const int b = bh >> 3, h = bh & 7;
    #pragma unroll
    for (int r = 0; r < 4; ++r) {
        int rr = tyq * 4 + r;                      // q-local row in C-frag
        float zi = 1.0f / __shfl(z, rr, 16);       // z[q=rr] lives at lane tx=rr
        size_t base = ((size_t)b * SS + q0 + wv * 16 + rr) * EE + h * DKK + tx;
        #pragma unroll
        for (int dt = 0; dt < 4; ++dt)
            attb[base + dt * 16] = f2bf(acc[dt][r] * zi);
    }
}

// ---------------------------------------------------------------------------
extern "C" void kernel_launch(void* const* d_in, const int* in_sizes, int n_in,
                              void* d_out, int out_size, void* d_ws, size_t ws_size,
                              hipStream_t stream)
{
    const float* x  = (const float*)d_in[0];
    const float* Wq = (const float*)d_in[1];
    const float* bq = (const float*)d_in[2];
    const float* Wk = (const float*)d_in[3];
    const float* bk = (const float*)d_in[4];
    const float* Wv = (const float*)d_in[5];
    const float* bv = (const float*)d_in[6];
    const float* Wo = (const float*)d_in[7];
    const float* bo = (const float*)d_in[8];
    // d_in[9] = kernel_params: unused (quantum circuit collapses to cos())

    char* w = (char*)d_ws;
    u16* xh    = (u16*)w;  w += (size_t)BS * EE * 2;               // 8 MB
    u16* xl    = (u16*)w;  w += (size_t)BS * EE * 2;               // 8 MB (aliases attb)
    u16* Wqkh  = (u16*)w;  w += (size_t)128 * EE * 2;              // 128 KB
    u16* Wqkl  = (u16*)w;  w += (size_t)128 * EE * 2;              // 128 KB
    u16* WvT   = (u16*)w;  w += (size_t)EE * EE * 2;               // 512 KB
    u16* WoT   = (u16*)w;  w += (size_t)EE * EE * 2;               // 512 KB
    u16* qf    = (u16*)w;  w += (size_t)BB * HH * SS * 8 * 2;      // 1 MB
    u16* kf    = (u16*)w;  w += (size_t)BB * HH * SS * 8 * 2;      // 1 MB
    u16* VT    = (u16*)w;  w += (size_t)BB * HH * DKK * SS * 2;    // 8 MB
    u16* attb  = xl;   // alias: xl consumed by qk_mfma before attn writes attb
    float* out = (float*)d_out;

    // P1: x -> bf16 hi/lo
    cvt2_kernel<<<dim3(BS * EE / 4 / 256), 256, 0, stream>>>(
        (const float4*)x, (uint2*)xh, (uint2*)xl, BS * EE / 4);
    // P2: Wq/Wk live cols -> packed transposed bf16 hi/lo
    wqk_pack_kernel<<<dim3(128), 256, 0, stream>>>(Wq, Wk, Wqkh, Wqkl);
    // P3: Wv, Wo -> transposed bf16
    wtrans_kernel<<<dim3(8, 8), 256, 0, stream>>>(Wv, WvT);
    wtrans_kernel<<<dim3(8, 8), 256, 0, stream>>>(Wo, WoT);
    // A: Q/K projection (MFMA, 3-pass double-bf16) + cos -> qf/kf f16
    qk_mfma_kernel<<<dim3(BS / 64, 2), 256, 0, stream>>>(
        xh, xl, Wqkh, Wqkl, bq, bk, qf, kf);
    // B: V projection, computed transposed -> VT[bh][d][s] f16 (MFMA bf16)
    mfma_gemm_kernel<1><<<dim3(EE / 64, BS / 64), 256, 0, stream>>>(
        WvT, xh, bv, nullptr, VT);
    // C: attention (all-MFMA sim+PV) -> attb bf16 [B*S][E]
    attn_v4_kernel<<<dim3(1024), 256, 0, stream>>>(qf, kf, VT, attb);
    // D: output projection + bias (MFMA bf16, fp32 out)
    mfma_gemm_kernel<0><<<dim3(BS / 64, EE / 64), 256, 0, stream>>>(
        attb, WoT, bo, out, nullptr);
}

// Round 5
// 97.448 us; speedup vs baseline: 4.9923x; 1.0527x over previous
//
#include <hip/hip_runtime.h>
#include <hip/hip_bf16.h>

// Problem constants
#define BB 4
#define SS 2048
#define EE 512
#define HH 8
#define DKK 64
#define NQQ 8
#define BS (BB * SS)   // 8192 rows

typedef __attribute__((ext_vector_type(8))) short bf16x8;
typedef __attribute__((ext_vector_type(4))) float f32x4;
typedef __attribute__((ext_vector_type(16))) float f32x16;
typedef _Float16 f16x4 __attribute__((ext_vector_type(4)));
typedef _Float16 f16x8 __attribute__((ext_vector_type(8)));
typedef unsigned short u16;
typedef unsigned int u32;

union U2H { uint2 u; f16x4 h; };
union U4H8 { uint4 u; f16x8 h; };

__device__ __forceinline__ u16 f2bf(float f) {
    union { float f; u32 u; } v; v.f = f;
    u32 r = v.u + 0x7fffu + ((v.u >> 16) & 1u);   // RNE
    return (u16)(r >> 16);
}
__device__ __forceinline__ float bf2f(u16 h) {
    union { u32 u; float f; } v; v.u = ((u32)h) << 16;
    return v.f;
}
__device__ __forceinline__ u16 f2h(float f) {
    _Float16 hv = (_Float16)f;
    return *reinterpret_cast<u16*>(&hv);
}

// ---------------------------------------------------------------------------
// P1: x fp32 -> xh (bf16) + xl (bf16 residual).
// ---------------------------------------------------------------------------
__global__ __launch_bounds__(256) void cvt2_kernel(
    const float4* __restrict__ in, uint2* __restrict__ xh, uint2* __restrict__ xl, int n4)
{
    int i = blockIdx.x * 256 + threadIdx.x;
    if (i >= n4) return;
    float4 a = in[i];
    u16 h0 = f2bf(a.x), h1 = f2bf(a.y), h2 = f2bf(a.z), h3 = f2bf(a.w);
    u16 l0 = f2bf(a.x - bf2f(h0)), l1 = f2bf(a.y - bf2f(h1));
    u16 l2 = f2bf(a.z - bf2f(h2)), l3 = f2bf(a.w - bf2f(h3));
    xh[i] = make_uint2((u32)h0 | ((u32)h1 << 16), (u32)h2 | ((u32)h3 << 16));
    xl[i] = make_uint2((u32)l0 | ((u32)l1 << 16), (u32)l2 | ((u32)l3 << 16));
}

// ---------------------------------------------------------------------------
// P2: pack+transpose the 64 live Q/K weight cols each into Wqk{h,l}[128][512].
// ---------------------------------------------------------------------------
__global__ __launch_bounds__(256) void wqk_pack_kernel(
    const float* __restrict__ Wq, const float* __restrict__ Wk,
    u16* __restrict__ Wh, u16* __restrict__ Wl)
{
    const int n = blockIdx.x;                  // 0..127
    const int col = (((n & 63) >> 3) << 6) | (n & 7);
    const float* src = (n < 64) ? Wq : Wk;
    for (int k = threadIdx.x; k < EE; k += 256) {
        float v = src[(size_t)k * EE + col];
        u16 h = f2bf(v);
        Wh[(size_t)n * EE + k] = h;
        Wl[(size_t)n * EE + k] = f2bf(v - bf2f(h));
    }
}

// ---------------------------------------------------------------------------
// P3: W [512][512] f32 -> WT [512][512] bf16 transposed (for Wv, Wo).
// ---------------------------------------------------------------------------
__global__ __launch_bounds__(256) void wtrans_kernel(
    const float* __restrict__ W, u16* __restrict__ WT)
{
    __shared__ float ts[64][65];
    const int kt0 = blockIdx.x * 64, nt0 = blockIdx.y * 64;
    const int tid = threadIdx.x;
    #pragma unroll
    for (int i = 0; i < 4; ++i) {
        int c = tid + i * 256;
        int kr = c >> 4, nc = (c & 15) * 4;
        float4 t = *reinterpret_cast<const float4*>(&W[(size_t)(kt0 + kr) * EE + nt0 + nc]);
        ts[kr][nc] = t.x; ts[kr][nc + 1] = t.y; ts[kr][nc + 2] = t.z; ts[kr][nc + 3] = t.w;
    }
    __syncthreads();
    const int n = tid >> 2, k0 = (tid & 3) * 16;
    u32 o[8];
    #pragma unroll
    for (int j = 0; j < 8; ++j) {
        o[j] = (u32)f2bf(ts[k0 + 2 * j][n]) | ((u32)f2bf(ts[k0 + 2 * j + 1][n]) << 16);
    }
    uint4* dst = reinterpret_cast<uint4*>(&WT[(size_t)(nt0 + n) * EE + kt0 + k0]);
    dst[0] = make_uint4(o[0], o[1], o[2], o[3]);
    dst[1] = make_uint4(o[4], o[5], o[6], o[7]);
}

// ---------------------------------------------------------------------------
// QK projection via MFMA, double-bf16 (3 passes). Epilogue: cos -> f16 qf/kf.
// ---------------------------------------------------------------------------
__global__ __launch_bounds__(256) void qk_mfma_kernel(
    const u16* __restrict__ xh, const u16* __restrict__ xl,
    const u16* __restrict__ Wh, const u16* __restrict__ Wl,
    const float* __restrict__ bq, const float* __restrict__ bk,
    u16* __restrict__ qf, u16* __restrict__ kf)
{
    __shared__ u16 Asl[64 * 64];
    __shared__ u16 Bsl[64 * 64];

    const int tid = threadIdx.x;
    const int lane = tid & 63;
    const int ww = tid >> 6;
    const int wr = ww >> 1, wc = ww & 1;
    const int tx = lane & 15, tyq = lane >> 4;
    const int m0 = blockIdx.x * 64;
    const int isK = blockIdx.y;
    const int nbase = isK * 64;

    const int c0 = tid, c1 = tid + 256;
    const int r0 = c0 >> 3, o0 = (c0 & 7) * 8, d0 = r0 * 64 + (((c0 & 7) ^ (r0 & 7)) * 8);
    const int r1 = c1 >> 3, o1 = (c1 & 7) * 8, d1 = r1 * 64 + (((c1 & 7) ^ (r1 & 7)) * 8);

    uint4 pa0, pa1, pb0, pb1;
    auto ldi = [&](int it) {
        int pass = it >> 3, k0 = (it & 7) * 64;
        const u16* Ab = (pass == 1) ? xl : xh;
        const u16* Bb = (pass == 2) ? Wl : Wh;
        pa0 = *reinterpret_cast<const uint4*>(&Ab[(size_t)(m0 + r0) * EE + k0 + o0]);
        pb0 = *reinterpret_cast<const uint4*>(&Bb[(size_t)(nbase + r0) * EE + k0 + o0]);
        pa1 = *reinterpret_cast<const uint4*>(&Ab[(size_t)(m0 + r1) * EE + k0 + o1]);
        pb1 = *reinterpret_cast<const uint4*>(&Bb[(size_t)(nbase + r1) * EE + k0 + o1]);
    };
    auto st = [&]() {
        *reinterpret_cast<uint4*>(&Asl[d0]) = pa0;
        *reinterpret_cast<uint4*>(&Bsl[d0]) = pb0;
        *reinterpret_cast<uint4*>(&Asl[d1]) = pa1;
        *reinterpret_cast<uint4*>(&Bsl[d1]) = pb1;
    };

    f32x4 acc[2][2];
    #pragma unroll
    for (int mt = 0; mt < 2; ++mt)
        #pragma unroll
        for (int nt = 0; nt < 2; ++nt) acc[mt][nt] = (f32x4)(0.f);

    const int bkx = tx & 7;
    ldi(0);
    for (int it = 0; it < 24; ++it) {
        __syncthreads();
        st();
        if (it < 23) ldi(it + 1);
        __syncthreads();
        #pragma unroll
        for (int kb = 0; kb < 2; ++kb) {
            bf16x8 af[2], bfg[2];
            const int kblk = ((kb * 4 + tyq) ^ bkx) * 8;
            #pragma unroll
            for (int mt = 0; mt < 2; ++mt)
                af[mt] = *reinterpret_cast<const bf16x8*>(&Asl[(wr * 32 + mt * 16 + tx) * 64 + kblk]);
            #pragma unroll
            for (int nt = 0; nt < 2; ++nt)
                bfg[nt] = *reinterpret_cast<const bf16x8*>(&Bsl[(wc * 32 + nt * 16 + tx) * 64 + kblk]);
            #pragma unroll
            for (int mt = 0; mt < 2; ++mt)
                #pragma unroll
                for (int nt = 0; nt < 2; ++nt)
                    acc[mt][nt] = __builtin_amdgcn_mfma_f32_16x16x32_bf16(
                        af[mt], bfg[nt], acc[mt][nt], 0, 0, 0);
        }
    }

    const float* bias = isK ? bk : bq;
    u16* dst = isK ? kf : qf;
    #pragma unroll
    for (int mt = 0; mt < 2; ++mt) {
        #pragma unroll
        for (int nt = 0; nt < 2; ++nt) {
            int nl = wc * 32 + nt * 16 + tx;
            int h = nl >> 3, f = nl & 7;
            float bcol = bias[h * 64 + f];
            #pragma unroll
            for (int r = 0; r < 4; ++r) {
                int s = m0 + wr * 32 + mt * 16 + tyq * 4 + r;
                float c = __cosf(acc[mt][nt][r] + bcol);
                size_t bh = (size_t)((s >> 11) * HH + h);
                dst[(bh * SS + (s & 2047)) * 8 + f] = f2h(c);
            }
        }
    }
}

// ---------------------------------------------------------------------------
// bf16 MFMA GEMM: out[m][n] = sum_k A[m][k] * Bm[n][k] (+ bias)
// MODE 0: out fp32 [8192][512], bias[n]. MODE 1: out f16 VT[b][h][d][s].
// ---------------------------------------------------------------------------
template<int MODE>
__global__ __launch_bounds__(256) void mfma_gemm_kernel(
    const u16* __restrict__ A, const u16* __restrict__ Bm,
    const float* __restrict__ bias, float* __restrict__ outf, u16* __restrict__ outb)
{
    __shared__ u16 Asl[64 * 64];
    __shared__ u16 Bsl[64 * 64];

    const int tid = threadIdx.x;
    const int lane = tid & 63;
    const int ww = tid >> 6;
    const int wr = ww >> 1, wc = ww & 1;
    const int tx = lane & 15, tyq = lane >> 4;
    const int m0 = blockIdx.x * 64, n0 = blockIdx.y * 64;

    const int c0 = tid, c1 = tid + 256;
    const int r0 = c0 >> 3, o0 = (c0 & 7) * 8, d0 = r0 * 64 + (((c0 & 7) ^ (r0 & 7)) * 8);
    const int r1 = c1 >> 3, o1 = (c1 & 7) * 8, d1 = r1 * 64 + (((c1 & 7) ^ (r1 & 7)) * 8);

    uint4 pa0, pa1, pb0, pb1;
    auto ld = [&](int ks) {
        int k0 = ks * 64;
        pa0 = *reinterpret_cast<const uint4*>(&A [(size_t)(m0 + r0) * EE + k0 + o0]);
        pb0 = *reinterpret_cast<const uint4*>(&Bm[(size_t)(n0 + r0) * EE + k0 + o0]);
        pa1 = *reinterpret_cast<const uint4*>(&A [(size_t)(m0 + r1) * EE + k0 + o1]);
        pb1 = *reinterpret_cast<const uint4*>(&Bm[(size_t)(n0 + r1) * EE + k0 + o1]);
    };
    auto st = [&]() {
        *reinterpret_cast<uint4*>(&Asl[d0]) = pa0;
        *reinterpret_cast<uint4*>(&Bsl[d0]) = pb0;
        *reinterpret_cast<uint4*>(&Asl[d1]) = pa1;
        *reinterpret_cast<uint4*>(&Bsl[d1]) = pb1;
    };

    f32x4 acc[2][2];
    #pragma unroll
    for (int mt = 0; mt < 2; ++mt)
        #pragma unroll
        for (int nt = 0; nt < 2; ++nt) acc[mt][nt] = (f32x4)(0.f);

    const int bkx = tx & 7;
    ld(0);
    for (int ks = 0; ks < 8; ++ks) {
        __syncthreads();
        st();
        if (ks < 7) ld(ks + 1);
        __syncthreads();
        #pragma unroll
        for (int kb = 0; kb < 2; ++kb) {
            bf16x8 af[2], bfg[2];
            const int kblk = ((kb * 4 + tyq) ^ bkx) * 8;
            #pragma unroll
            for (int mt = 0; mt < 2; ++mt)
                af[mt] = *reinterpret_cast<const bf16x8*>(&Asl[(wr * 32 + mt * 16 + tx) * 64 + kblk]);
            #pragma unroll
            for (int nt = 0; nt < 2; ++nt)
                bfg[nt] = *reinterpret_cast<const bf16x8*>(&Bsl[(wc * 32 + nt * 16 + tx) * 64 + kblk]);
            #pragma unroll
            for (int mt = 0; mt < 2; ++mt)
                #pragma unroll
                for (int nt = 0; nt < 2; ++nt)
                    acc[mt][nt] = __builtin_amdgcn_mfma_f32_16x16x32_bf16(
                        af[mt], bfg[nt], acc[mt][nt], 0, 0, 0);
        }
    }

    #pragma unroll
    for (int mt = 0; mt < 2; ++mt) {
        #pragma unroll
        for (int nt = 0; nt < 2; ++nt) {
            int gcol = n0 + wc * 32 + nt * 16 + tx;
            float bcol = (MODE == 0) ? bias[gcol] : 0.f;
            #pragma unroll
            for (int r = 0; r < 4; ++r) {
                int grow = m0 + wr * 32 + mt * 16 + tyq * 4 + r;
                float v = acc[mt][nt][r];
                if (MODE == 0) {
                    outf[(size_t)grow * EE + gcol] = v + bcol;
                } else {
                    float vb = v + bias[grow];
                    size_t addr = ((size_t)((gcol >> 11) * 8 + (grow >> 6))) * (64 * 2048)
                                + (size_t)(grow & 63) * 2048 + (gcol & 2047);
                    outb[addr] = f2h(vb);
                }
            }
        }
    }
}

// ---------------------------------------------------------------------------
// Attention v5: 32x32x16 f16 MFMAs, lane-local sim->PV handoff.
// Wave = 32 q x 64 d; block = 4 waves (128 q); one (b,h) per 16 blocks.
// Per 64-k tile: 2 sims (k=16 contraction, feats 8 + 8 zero-pad) + 8 PV.
// sim C-frag: lane (q=l&31, hi) holds w[(r&3)+8*(r>>2)+4hi][q], r=0..15.
// V LDS rows permuted by tau = swap bits2<->3 of low4(row): then PV A-frag
// slot 8hi+j == sim reg[8c+j] (lane-local, in order); B-frag = one b128.
// 16B-block XOR swizzle (pb = blk ^ (d&7)) => 8-lane full-bank coverage.
// K-frags read directly from L2 (32 KB/bh). No kfl, no w LDS.
// ---------------------------------------------------------------------------
__global__ __launch_bounds__(256) void attn_v5_kernel(
    const u16* __restrict__ qf, const u16* __restrict__ kf,
    const u16* __restrict__ VT, u16* __restrict__ attb)
{
    __shared__ u16 vtl[64 * 64];   // f16 [d][kk], tau-permuted, swizzled: 8 KB

    const int tid = threadIdx.x;
    const int lane = tid & 63;
    const int wq = tid >> 6;           // wave -> q sub-block (32 q)
    const int l31 = lane & 31;
    const int hi = lane >> 5;

    // XCD-aware swizzle: all 16 q-blocks of a (b,h) on one XCD
    const int bid = blockIdx.x;
    const int xcd = bid & 7, sub = bid >> 3;     // sub 0..63
    const int bh = (xcd << 2) | (sub >> 4);      // 0..31
    const int q0 = (sub & 15) * 128;

    const u16* __restrict__ qfb = qf + (size_t)bh * SS * 8;
    const u16* __restrict__ kfb = kf + (size_t)bh * SS * 8;
    const u16* __restrict__ VTb = VT + (size_t)bh * DKK * SS;

    const uint4 z4 = make_uint4(0u, 0u, 0u, 0u);

    // Q B-frag (loop-invariant): B[k=8hi+j][n=q=l31]; feats 8..15 are pad=0
    U4H8 qb;
    qb.u = hi ? z4 : *reinterpret_cast<const uint4*>(&qfb[(size_t)(q0 + wq * 32 + l31) * 8]);
    const f16x8 QB = qb.h;

    // V staging: thread covers (d, bk) for c = tid, tid+256
    const int wd0 = tid >> 3, wbk = tid & 7;
    const int B0 = (wbk >> 1) * 2;
    const int offu = (wbk & 1) * 4;                       // u16 offset in block
    const int w0a = wd0 * 64 + ((B0 ^ (wd0 & 7)) * 8) + offu;
    const int w0b = wd0 * 64 + (((B0 + 1) ^ (wd0 & 7)) * 8) + offu;
    const int wd1 = wd0 + 32;
    const int w1a = wd1 * 64 + ((B0 ^ (wd1 & 7)) * 8) + offu;
    const int w1b = wd1 * 64 + (((B0 + 1) ^ (wd1 & 7)) * 8) + offu;

    uint4 pv0, pv1;
    auto ldv = [&](int kt) {
        pv0 = *reinterpret_cast<const uint4*>(&VTb[(size_t)wd0 * SS + kt + wbk * 8]);
        pv1 = *reinterpret_cast<const uint4*>(&VTb[(size_t)wd1 * SS + kt + wbk * 8]);
    };
    // tau: global 16B (rows bk*8..bk*8+7) splits into two 8B at kk0, kk0+8
    auto stv = [&]() {
        *reinterpret_cast<uint2*>(&vtl[w0a]) = make_uint2(pv0.x, pv0.y);
        *reinterpret_cast<uint2*>(&vtl[w0b]) = make_uint2(pv0.z, pv0.w);
        *reinterpret_cast<uint2*>(&vtl[w1a]) = make_uint2(pv1.x, pv1.y);
        *reinterpret_cast<uint2*>(&vtl[w1b]) = make_uint2(pv1.z, pv1.w);
    };

    f32x16 acc0 = (f32x16)(0.f);
    f32x16 acc1 = (f32x16)(0.f);
    float z = 0.f;

    const int vr0 = l31 * 64;              // dt=0 row base (d = l31)
    const int vr1 = (32 + l31) * 64;       // dt=1
    const int bx = l31 & 7;

    ldv(0);
    for (int kt = 0; kt < SS; kt += 64) {
        __syncthreads();
        stv();
        if (kt + 64 < SS) ldv(kt + 64);
        __syncthreads();

        // K A-frags for both sims (issue both loads early; L2-resident)
        U4H8 ka0, ka1;
        ka0.u = hi ? z4 : *reinterpret_cast<const uint4*>(&kfb[(size_t)(kt + l31) * 8]);
        ka1.u = hi ? z4 : *reinterpret_cast<const uint4*>(&kfb[(size_t)(kt + 32 + l31) * 8]);

        #pragma unroll
        for (int s = 0; s < 2; ++s) {
            f32x16 sim = (f32x16)(0.f);
            sim = __builtin_amdgcn_mfma_f32_32x32x16_f16(
                s ? ka1.h : ka0.h, QB, sim, 0, 0, 0);

            // sim in [-8,8]: single-pass softmax, no max subtraction
            float w[16];
            #pragma unroll
            for (int r = 0; r < 16; ++r) w[r] = __expf(sim[r]);
            float zp = 0.f;
            #pragma unroll
            for (int r = 0; r < 8; ++r) zp += (w[2 * r] + w[2 * r + 1]);
            z += zp;

            #pragma unroll
            for (int c = 0; c < 2; ++c) {
                f16x8 PA;
                #pragma unroll
                for (int j = 0; j < 8; ++j) PA[j] = (_Float16)w[8 * c + j];
                const int e = s * 4 + c * 2;
                f16x8 VB0 = *reinterpret_cast<const f16x8*>(&vtl[vr0 + (((e + hi) ^ bx) * 8)]);
                acc0 = __builtin_amdgcn_mfma_f32_32x32x16_f16(PA, VB0, acc0, 0, 0, 0);
                f16x8 VB1 = *reinterpret_cast<const f16x8*>(&vtl[vr1 + (((e + hi) ^ bx) * 8)]);
                acc1 = __builtin_amdgcn_mfma_f32_32x32x16_f16(PA, VB1, acc1, 0, 0, 0);
            }
        }
    }

    // z: lanes l and l+32 hold complementary row-partials for q = l31
    z += __shfl_xor(z, 32, 64);
    float zinv = 1.0f / z;

    const int b = bh >> 3, h = bh & 7;
    #pragma unroll
    for (int r = 0; r < 16; ++r) {
        int qrow = (r & 3) + 8 * (r >> 2) + 4 * hi;
        float zi = __shfl(zinv, qrow, 32);    // zinv of q=qrow within 32-group
        size_t base = ((size_t)b * SS + q0 + wq * 32 + qrow) * EE + h * DKK + l31;
        attb[base]      = f2bf(acc0[r] * zi);
        attb[base + 32] = f2bf(acc1[r] * zi);
    }
}

// ---------------------------------------------------------------------------
extern "C" void kernel_launch(void* const* d_in, const int* in_sizes, int n_in,
                              void* d_out, int out_size, void* d_ws, size_t ws_size,
                              hipStream_t stream)
{
    const float* x  = (const float*)d_in[0];
    const float* Wq = (const float*)d_in[1];
    const float* bq = (const float*)d_in[2];
    const float* Wk = (const float*)d_in[3];
    const float* bk = (const float*)d_in[4];
    const float* Wv = (const float*)d_in[5];
    const float* bv = (const float*)d_in[6];
    const float* Wo = (const float*)d_in[7];
    const float* bo = (const float*)d_in[8];
    // d_in[9] = kernel_params: unused (quantum circuit collapses to cos())

    char* w = (char*)d_ws;
    u16* xh    = (u16*)w;  w += (size_t)BS * EE * 2;               // 8 MB
    u16* xl    = (u16*)w;  w += (size_t)BS * EE * 2;               // 8 MB (aliases attb)
    u16* Wqkh  = (u16*)w;  w += (size_t)128 * EE * 2;              // 128 KB
    u16* Wqkl  = (u16*)w;  w += (size_t)128 * EE * 2;              // 128 KB
    u16* WvT   = (u16*)w;  w += (size_t)EE * EE * 2;               // 512 KB
    u16* WoT   = (u16*)w;  w += (size_t)EE * EE * 2;               // 512 KB
    u16* qf    = (u16*)w;  w += (size_t)BB * HH * SS * 8 * 2;      // 1 MB
    u16* kf    = (u16*)w;  w += (size_t)BB * HH * SS * 8 * 2;      // 1 MB
    u16* VT    = (u16*)w;  w += (size_t)BB * HH * DKK * SS * 2;    // 8 MB
    u16* attb  = xl;   // alias: xl consumed by qk_mfma before attn writes attb
    float* out = (float*)d_out;

    // P1: x -> bf16 hi/lo
    cvt2_kernel<<<dim3(BS * EE / 4 / 256), 256, 0, stream>>>(
        (const float4*)x, (uint2*)xh, (uint2*)xl, BS * EE / 4);
    // P2: Wq/Wk live cols -> packed transposed bf16 hi/lo
    wqk_pack_kernel<<<dim3(128), 256, 0, stream>>>(Wq, Wk, Wqkh, Wqkl);
    // P3: Wv, Wo -> transposed bf16
    wtrans_kernel<<<dim3(8, 8), 256, 0, stream>>>(Wv, WvT);
    wtrans_kernel<<<dim3(8, 8), 256, 0, stream>>>(Wo, WoT);
    // A: Q/K projection (MFMA, 3-pass double-bf16) + cos -> qf/kf f16
    qk_mfma_kernel<<<dim3(BS / 64, 2), 256, 0, stream>>>(
        xh, xl, Wqkh, Wqkl, bq, bk, qf, kf);
    // B: V projection, computed transposed -> VT[bh][d][s] f16 (MFMA bf16)
    mfma_gemm_kernel<1><<<dim3(EE / 64, BS / 64), 256, 0, stream>>>(
        WvT, xh, bv, nullptr, VT);
    // C: attention (32x32 MFMA sim+PV, tau-permuted V) -> attb bf16 [B*S][E]
    attn_v5_kernel<<<dim3(512), 256, 0, stream>>>(qf, kf, VT, attb);
    // D: output projection + bias (MFMA bf16, fp32 out)
    mfma_gemm_kernel<0><<<dim3(BS / 64, EE / 64), 256, 0, stream>>>(
        attb, WoT, bo, out, nullptr);
}

// Round 6
// 89.972 us; speedup vs baseline: 5.4071x; 1.0831x over previous
//
#include <hip/hip_runtime.h>
#include <hip/hip_bf16.h>

// Problem constants
#define BB 4
#define SS 2048
#define EE 512
#define HH 8
#define DKK 64
#define NQQ 8
#define BS (BB * SS)   // 8192 rows

typedef __attribute__((ext_vector_type(8))) short bf16x8;
typedef __attribute__((ext_vector_type(4))) float f32x4;
typedef __attribute__((ext_vector_type(16))) float f32x16;
typedef _Float16 f16x4 __attribute__((ext_vector_type(4)));
typedef _Float16 f16x8 __attribute__((ext_vector_type(8)));
typedef unsigned short u16;
typedef unsigned int u32;

union U2H { uint2 u; f16x4 h; };
union U4H8 { uint4 u; f16x8 h; };

__device__ __forceinline__ u16 f2bf(float f) {
    union { float f; u32 u; } v; v.f = f;
    u32 r = v.u + 0x7fffu + ((v.u >> 16) & 1u);   // RNE
    return (u16)(r >> 16);
}
__device__ __forceinline__ float bf2f(u16 h) {
    union { u32 u; float f; } v; v.u = ((u32)h) << 16;
    return v.f;
}
__device__ __forceinline__ u16 f2h(float f) {
    _Float16 hv = (_Float16)f;
    return *reinterpret_cast<u16*>(&hv);
}

// ---------------------------------------------------------------------------
// P1: x fp32 -> xh (bf16) + xl (bf16 residual).
// ---------------------------------------------------------------------------
__global__ __launch_bounds__(256) void cvt2_kernel(
    const float4* __restrict__ in, uint2* __restrict__ xh, uint2* __restrict__ xl, int n4)
{
    int i = blockIdx.x * 256 + threadIdx.x;
    if (i >= n4) return;
    float4 a = in[i];
    u16 h0 = f2bf(a.x), h1 = f2bf(a.y), h2 = f2bf(a.z), h3 = f2bf(a.w);
    u16 l0 = f2bf(a.x - bf2f(h0)), l1 = f2bf(a.y - bf2f(h1));
    u16 l2 = f2bf(a.z - bf2f(h2)), l3 = f2bf(a.w - bf2f(h3));
    xh[i] = make_uint2((u32)h0 | ((u32)h1 << 16), (u32)h2 | ((u32)h3 << 16));
    xl[i] = make_uint2((u32)l0 | ((u32)l1 << 16), (u32)l2 | ((u32)l3 << 16));
}

// ---------------------------------------------------------------------------
// P2: pack+transpose the 64 live Q/K weight cols each into Wqk{h,l}[128][512].
// ---------------------------------------------------------------------------
__global__ __launch_bounds__(256) void wqk_pack_kernel(
    const float* __restrict__ Wq, const float* __restrict__ Wk,
    u16* __restrict__ Wh, u16* __restrict__ Wl)
{
    const int n = blockIdx.x;                  // 0..127
    const int col = (((n & 63) >> 3) << 6) | (n & 7);
    const float* src = (n < 64) ? Wq : Wk;
    for (int k = threadIdx.x; k < EE; k += 256) {
        float v = src[(size_t)k * EE + col];
        u16 h = f2bf(v);
        Wh[(size_t)n * EE + k] = h;
        Wl[(size_t)n * EE + k] = f2bf(v - bf2f(h));
    }
}

// ---------------------------------------------------------------------------
// P3: W [512][512] f32 -> WT [512][512] bf16 transposed (for Wv, Wo).
// ---------------------------------------------------------------------------
__global__ __launch_bounds__(256) void wtrans_kernel(
    const float* __restrict__ W, u16* __restrict__ WT)
{
    __shared__ float ts[64][65];
    const int kt0 = blockIdx.x * 64, nt0 = blockIdx.y * 64;
    const int tid = threadIdx.x;
    #pragma unroll
    for (int i = 0; i < 4; ++i) {
        int c = tid + i * 256;
        int kr = c >> 4, nc = (c & 15) * 4;
        float4 t = *reinterpret_cast<const float4*>(&W[(size_t)(kt0 + kr) * EE + nt0 + nc]);
        ts[kr][nc] = t.x; ts[kr][nc + 1] = t.y; ts[kr][nc + 2] = t.z; ts[kr][nc + 3] = t.w;
    }
    __syncthreads();
    const int n = tid >> 2, k0 = (tid & 3) * 16;
    u32 o[8];
    #pragma unroll
    for (int j = 0; j < 8; ++j) {
        o[j] = (u32)f2bf(ts[k0 + 2 * j][n]) | ((u32)f2bf(ts[k0 + 2 * j + 1][n]) << 16);
    }
    uint4* dst = reinterpret_cast<uint4*>(&WT[(size_t)(nt0 + n) * EE + kt0 + k0]);
    dst[0] = make_uint4(o[0], o[1], o[2], o[3]);
    dst[1] = make_uint4(o[4], o[5], o[6], o[7]);
}

// ---------------------------------------------------------------------------
// QK projection via MFMA, double-bf16 (3 passes). Epilogue: cos -> f16 qf/kf.
// ---------------------------------------------------------------------------
__global__ __launch_bounds__(256) void qk_mfma_kernel(
    const u16* __restrict__ xh, const u16* __restrict__ xl,
    const u16* __restrict__ Wh, const u16* __restrict__ Wl,
    const float* __restrict__ bq, const float* __restrict__ bk,
    u16* __restrict__ qf, u16* __restrict__ kf)
{
    __shared__ u16 Asl[64 * 64];
    __shared__ u16 Bsl[64 * 64];

    const int tid = threadIdx.x;
    const int lane = tid & 63;
    const int ww = tid >> 6;
    const int wr = ww >> 1, wc = ww & 1;
    const int tx = lane & 15, tyq = lane >> 4;
    const int m0 = blockIdx.x * 64;
    const int isK = blockIdx.y;
    const int nbase = isK * 64;

    const int c0 = tid, c1 = tid + 256;
    const int r0 = c0 >> 3, o0 = (c0 & 7) * 8, d0 = r0 * 64 + (((c0 & 7) ^ (r0 & 7)) * 8);
    const int r1 = c1 >> 3, o1 = (c1 & 7) * 8, d1 = r1 * 64 + (((c1 & 7) ^ (r1 & 7)) * 8);

    uint4 pa0, pa1, pb0, pb1;
    auto ldi = [&](int it) {
        int pass = it >> 3, k0 = (it & 7) * 64;
        const u16* Ab = (pass == 1) ? xl : xh;
        const u16* Bb = (pass == 2) ? Wl : Wh;
        pa0 = *reinterpret_cast<const uint4*>(&Ab[(size_t)(m0 + r0) * EE + k0 + o0]);
        pb0 = *reinterpret_cast<const uint4*>(&Bb[(size_t)(nbase + r0) * EE + k0 + o0]);
        pa1 = *reinterpret_cast<const uint4*>(&Ab[(size_t)(m0 + r1) * EE + k0 + o1]);
        pb1 = *reinterpret_cast<const uint4*>(&Bb[(size_t)(nbase + r1) * EE + k0 + o1]);
    };
    auto st = [&]() {
        *reinterpret_cast<uint4*>(&Asl[d0]) = pa0;
        *reinterpret_cast<uint4*>(&Bsl[d0]) = pb0;
        *reinterpret_cast<uint4*>(&Asl[d1]) = pa1;
        *reinterpret_cast<uint4*>(&Bsl[d1]) = pb1;
    };

    f32x4 acc[2][2];
    #pragma unroll
    for (int mt = 0; mt < 2; ++mt)
        #pragma unroll
        for (int nt = 0; nt < 2; ++nt) acc[mt][nt] = (f32x4)(0.f);

    const int bkx = tx & 7;
    ldi(0);
    for (int it = 0; it < 24; ++it) {
        __syncthreads();
        st();
        if (it < 23) ldi(it + 1);
        __syncthreads();
        #pragma unroll
        for (int kb = 0; kb < 2; ++kb) {
            bf16x8 af[2], bfg[2];
            const int kblk = ((kb * 4 + tyq) ^ bkx) * 8;
            #pragma unroll
            for (int mt = 0; mt < 2; ++mt)
                af[mt] = *reinterpret_cast<const bf16x8*>(&Asl[(wr * 32 + mt * 16 + tx) * 64 + kblk]);
            #pragma unroll
            for (int nt = 0; nt < 2; ++nt)
                bfg[nt] = *reinterpret_cast<const bf16x8*>(&Bsl[(wc * 32 + nt * 16 + tx) * 64 + kblk]);
            #pragma unroll
            for (int mt = 0; mt < 2; ++mt)
                #pragma unroll
                for (int nt = 0; nt < 2; ++nt)
                    acc[mt][nt] = __builtin_amdgcn_mfma_f32_16x16x32_bf16(
                        af[mt], bfg[nt], acc[mt][nt], 0, 0, 0);
        }
    }

    const float* bias = isK ? bk : bq;
    u16* dst = isK ? kf : qf;
    #pragma unroll
    for (int mt = 0; mt < 2; ++mt) {
        #pragma unroll
        for (int nt = 0; nt < 2; ++nt) {
            int nl = wc * 32 + nt * 16 + tx;
            int h = nl >> 3, f = nl & 7;
            float bcol = bias[h * 64 + f];
            #pragma unroll
            for (int r = 0; r < 4; ++r) {
                int s = m0 + wr * 32 + mt * 16 + tyq * 4 + r;
                float c = __cosf(acc[mt][nt][r] + bcol);
                size_t bh = (size_t)((s >> 11) * HH + h);
                dst[(bh * SS + (s & 2047)) * 8 + f] = f2h(c);
            }
        }
    }
}

// ---------------------------------------------------------------------------
// bf16 MFMA GEMM: out[m][n] = sum_k A[m][k] * Bm[n][k] (+ bias)
// MODE 0: out fp32 [8192][512], bias[n]. MODE 1: out f16 VT[b][h][d][s].
// ---------------------------------------------------------------------------
template<int MODE>
__global__ __launch_bounds__(256) void mfma_gemm_kernel(
    const u16* __restrict__ A, const u16* __restrict__ Bm,
    const float* __restrict__ bias, float* __restrict__ outf, u16* __restrict__ outb)
{
    __shared__ u16 Asl[64 * 64];
    __shared__ u16 Bsl[64 * 64];

    const int tid = threadIdx.x;
    const int lane = tid & 63;
    const int ww = tid >> 6;
    const int wr = ww >> 1, wc = ww & 1;
    const int tx = lane & 15, tyq = lane >> 4;
    const int m0 = blockIdx.x * 64, n0 = blockIdx.y * 64;

    const int c0 = tid, c1 = tid + 256;
    const int r0 = c0 >> 3, o0 = (c0 & 7) * 8, d0 = r0 * 64 + (((c0 & 7) ^ (r0 & 7)) * 8);
    const int r1 = c1 >> 3, o1 = (c1 & 7) * 8, d1 = r1 * 64 + (((c1 & 7) ^ (r1 & 7)) * 8);

    uint4 pa0, pa1, pb0, pb1;
    auto ld = [&](int ks) {
        int k0 = ks * 64;
        pa0 = *reinterpret_cast<const uint4*>(&A [(size_t)(m0 + r0) * EE + k0 + o0]);
        pb0 = *reinterpret_cast<const uint4*>(&Bm[(size_t)(n0 + r0) * EE + k0 + o0]);
        pa1 = *reinterpret_cast<const uint4*>(&A [(size_t)(m0 + r1) * EE + k0 + o1]);
        pb1 = *reinterpret_cast<const uint4*>(&Bm[(size_t)(n0 + r1) * EE + k0 + o1]);
    };
    auto st = [&]() {
        *reinterpret_cast<uint4*>(&Asl[d0]) = pa0;
        *reinterpret_cast<uint4*>(&Bsl[d0]) = pb0;
        *reinterpret_cast<uint4*>(&Asl[d1]) = pa1;
        *reinterpret_cast<uint4*>(&Bsl[d1]) = pb1;
    };

    f32x4 acc[2][2];
    #pragma unroll
    for (int mt = 0; mt < 2; ++mt)
        #pragma unroll
        for (int nt = 0; nt < 2; ++nt) acc[mt][nt] = (f32x4)(0.f);

    const int bkx = tx & 7;
    ld(0);
    for (int ks = 0; ks < 8; ++ks) {
        __syncthreads();
        st();
        if (ks < 7) ld(ks + 1);
        __syncthreads();
        #pragma unroll
        for (int kb = 0; kb < 2; ++kb) {
            bf16x8 af[2], bfg[2];
            const int kblk = ((kb * 4 + tyq) ^ bkx) * 8;
            #pragma unroll
            for (int mt = 0; mt < 2; ++mt)
                af[mt] = *reinterpret_cast<const bf16x8*>(&Asl[(wr * 32 + mt * 16 + tx) * 64 + kblk]);
            #pragma unroll
            for (int nt = 0; nt < 2; ++nt)
                bfg[nt] = *reinterpret_cast<const bf16x8*>(&Bsl[(wc * 32 + nt * 16 + tx) * 64 + kblk]);
            #pragma unroll
            for (int mt = 0; mt < 2; ++mt)
                #pragma unroll
                for (int nt = 0; nt < 2; ++nt)
                    acc[mt][nt] = __builtin_amdgcn_mfma_f32_16x16x32_bf16(
                        af[mt], bfg[nt], acc[mt][nt], 0, 0, 0);
        }
    }

    #pragma unroll
    for (int mt = 0; mt < 2; ++mt) {
        #pragma unroll
        for (int nt = 0; nt < 2; ++nt) {
            int gcol = n0 + wc * 32 + nt * 16 + tx;
            float bcol = (MODE == 0) ? bias[gcol] : 0.f;
            #pragma unroll
            for (int r = 0; r < 4; ++r) {
                int grow = m0 + wr * 32 + mt * 16 + tyq * 4 + r;
                float v = acc[mt][nt][r];
                if (MODE == 0) {
                    outf[(size_t)grow * EE + gcol] = v + bcol;
                } else {
                    float vb = v + bias[grow];
                    size_t addr = ((size_t)((gcol >> 11) * 8 + (grow >> 6))) * (64 * 2048)
                                + (size_t)(grow & 63) * 2048 + (gcol & 2047);
                    outb[addr] = f2h(vb);
                }
            }
        }
    }
}

// ---------------------------------------------------------------------------
// Attention v6: 32x32x16 f16 MFMAs, lane-local sim->PV handoff (as v5), plus:
//  - k-split: 4 waves = 2 q-sub-blocks (32 q) x 2 k-slices (1024 k each);
//    grid 1024 blocks = 4 blocks/CU = 4 waves/SIMD (was 2).
//  - double-buffered LDS V tiles (2 slices x 2 bufs, 32 KB): ONE barrier
//    per k-tile; next tile's V + K loads issued before compute (T14-lite).
//  - end: k-slices combine via stride-33 (conflict-free) LDS exchange.
// ---------------------------------------------------------------------------
__global__ __launch_bounds__(256, 4) void attn_v6_kernel(
    const u16* __restrict__ qf, const u16* __restrict__ kf,
    const u16* __restrict__ VT, u16* __restrict__ attb)
{
    __shared__ u16 vtl[2][2][64 * 64];   // [slice][buf][d*64+kk], 32 KB

    const int tid = threadIdx.x;
    const int lane = tid & 63;
    const int wv = tid >> 6;
    const int kslice = wv >> 1;          // 0,1: k range [kslice*1024, +1024)
    const int qw = wv & 1;               // q sub-block of 32
    const int l31 = lane & 31;
    const int hi = lane >> 5;

    // XCD-aware swizzle: all 32 q-blocks of a (b,h) on one XCD
    const int bid = blockIdx.x;
    const int xcd = bid & 7, sub = bid >> 3;     // sub 0..127
    const int bh = (xcd << 2) | (sub >> 5);      // 0..31
    const int q0 = (sub & 31) * 64;

    const u16* __restrict__ qfb = qf + (size_t)bh * SS * 8;
    const u16* __restrict__ kfb = kf + (size_t)bh * SS * 8;
    const u16* __restrict__ VTb = VT + (size_t)bh * DKK * SS;

    const uint4 z4 = make_uint4(0u, 0u, 0u, 0u);

    // Q B-frag (loop-invariant): B[k=8hi+j][n=q=l31]; feats 8..15 pad=0
    U4H8 qb;
    qb.u = hi ? z4 : *reinterpret_cast<const uint4*>(&qfb[(size_t)(q0 + qw * 32 + l31) * 8]);
    const f16x8 QB = qb.h;

    // V staging mapping (identical tau-permute + XOR swizzle as v5), per slice
    const int wd0 = tid >> 3, wbk = tid & 7;
    const int B0 = (wbk >> 1) * 2;
    const int offu = (wbk & 1) * 4;
    const int w0a = wd0 * 64 + ((B0 ^ (wd0 & 7)) * 8) + offu;
    const int w0b = wd0 * 64 + (((B0 + 1) ^ (wd0 & 7)) * 8) + offu;
    const int wd1 = wd0 + 32;
    const int w1a = wd1 * 64 + ((B0 ^ (wd1 & 7)) * 8) + offu;
    const int w1b = wd1 * 64 + (((B0 + 1) ^ (wd1 & 7)) * 8) + offu;

    uint4 pv[2][2];
    auto ldv = [&](int t) {
        #pragma unroll
        for (int s = 0; s < 2; ++s) {
            int kt = s * 1024 + t * 64;
            pv[s][0] = *reinterpret_cast<const uint4*>(&VTb[(size_t)wd0 * SS + kt + wbk * 8]);
            pv[s][1] = *reinterpret_cast<const uint4*>(&VTb[(size_t)wd1 * SS + kt + wbk * 8]);
        }
    };
    auto stv = [&](int buf) {
        #pragma unroll
        for (int s = 0; s < 2; ++s) {
            u16* base = &vtl[s][buf][0];
            *reinterpret_cast<uint2*>(&base[w0a]) = make_uint2(pv[s][0].x, pv[s][0].y);
            *reinterpret_cast<uint2*>(&base[w0b]) = make_uint2(pv[s][0].z, pv[s][0].w);
            *reinterpret_cast<uint2*>(&base[w1a]) = make_uint2(pv[s][1].x, pv[s][1].y);
            *reinterpret_cast<uint2*>(&base[w1b]) = make_uint2(pv[s][1].z, pv[s][1].w);
        }
    };

    f32x16 acc0 = (f32x16)(0.f), acc1 = (f32x16)(0.f);
    float z = 0.f;

    const int vr0 = l31 * 64, vr1 = (32 + l31) * 64;
    const int bx = l31 & 7;
    const int ks_off = kslice * 1024;

    // K fragments: prefetched one tile ahead (L2-resident, coalesced 512B)
    U4H8 kc0, kc1, kn0, kn1;
    auto ldk = [&](int t, U4H8& a, U4H8& b) {
        int kt = ks_off + t * 64;
        a.u = hi ? z4 : *reinterpret_cast<const uint4*>(&kfb[(size_t)(kt + l31) * 8]);
        b.u = hi ? z4 : *reinterpret_cast<const uint4*>(&kfb[(size_t)(kt + 32 + l31) * 8]);
    };

    ldv(0);
    ldk(0, kc0, kc1);
    stv(0);
    __syncthreads();

    for (int t = 0; t < 16; ++t) {
        const int cur = t & 1;
        if (t < 15) { ldv(t + 1); ldk(t + 1, kn0, kn1); }

        const u16* vbase = &vtl[kslice][cur][0];
        #pragma unroll
        for (int s = 0; s < 2; ++s) {
            f32x16 sim = (f32x16)(0.f);
            sim = __builtin_amdgcn_mfma_f32_32x32x16_f16(
                s ? kc1.h : kc0.h, QB, sim, 0, 0, 0);

            // sim in [-8,8]: single-pass softmax, no max subtraction
            float w[16];
            #pragma unroll
            for (int r = 0; r < 16; ++r) w[r] = __expf(sim[r]);
            float zp = 0.f;
            #pragma unroll
            for (int r = 0; r < 8; ++r) zp += (w[2 * r] + w[2 * r + 1]);
            z += zp;

            #pragma unroll
            for (int c = 0; c < 2; ++c) {
                f16x8 PA;
                #pragma unroll
                for (int j = 0; j < 8; ++j) PA[j] = (_Float16)w[8 * c + j];
                const int e = s * 4 + c * 2;
                f16x8 VB0 = *reinterpret_cast<const f16x8*>(&vbase[vr0 + (((e + hi) ^ bx) * 8)]);
                acc0 = __builtin_amdgcn_mfma_f32_32x32x16_f16(PA, VB0, acc0, 0, 0, 0);
                f16x8 VB1 = *reinterpret_cast<const f16x8*>(&vbase[vr1 + (((e + hi) ^ bx) * 8)]);
                acc1 = __builtin_amdgcn_mfma_f32_32x32x16_f16(PA, VB1, acc1, 0, 0, 0);
            }
        }

        if (t < 15) stv(cur ^ 1);
        __syncthreads();
        kc0 = kn0; kc1 = kn1;
    }

    // combine k-slices (LDS reused as fp32 scratch; stride 33 = conflict-free)
    float* fsh = reinterpret_cast<float*>(&vtl[0][0][0]);
    const int cbase = (qw * 64 + lane) * 33;
    if (kslice == 1) {
        #pragma unroll
        for (int r = 0; r < 16; ++r) {
            fsh[cbase + r] = acc0[r];
            fsh[cbase + 16 + r] = acc1[r];
        }
        fsh[cbase + 32] = z;
    }
    __syncthreads();
    if (kslice == 0) {
        #pragma unroll
        for (int r = 0; r < 16; ++r) {
            acc0[r] += fsh[cbase + r];
            acc1[r] += fsh[cbase + 16 + r];
        }
        z += fsh[cbase + 32];
        z += __shfl_xor(z, 32, 64);     // combine hi halves
        float zinv = 1.0f / z;

        const int b = bh >> 3, h = bh & 7;
        #pragma unroll
        for (int r = 0; r < 16; ++r) {
            int qrow = (r & 3) + 8 * (r >> 2) + 4 * hi;
            float zi = __shfl(zinv, qrow, 32);
            size_t base = ((size_t)b * SS + q0 + qw * 32 + qrow) * EE + h * DKK + l31;
            attb[base]      = f2bf(acc0[r] * zi);
            attb[base + 32] = f2bf(acc1[r] * zi);
        }
    }
}

// ---------------------------------------------------------------------------
extern "C" void kernel_launch(void* const* d_in, const int* in_sizes, int n_in,
                              void* d_out, int out_size, void* d_ws, size_t ws_size,
                              hipStream_t stream)
{
    const float* x  = (const float*)d_in[0];
    const float* Wq = (const float*)d_in[1];
    const float* bq = (const float*)d_in[2];
    const float* Wk = (const float*)d_in[3];
    const float* bk = (const float*)d_in[4];
    const float* Wv = (const float*)d_in[5];
    const float* bv = (const float*)d_in[6];
    const float* Wo = (const float*)d_in[7];
    const float* bo = (const float*)d_in[8];
    // d_in[9] = kernel_params: unused (quantum circuit collapses to cos())

    char* w = (char*)d_ws;
    u16* xh    = (u16*)w;  w += (size_t)BS * EE * 2;               // 8 MB
    u16* xl    = (u16*)w;  w += (size_t)BS * EE * 2;               // 8 MB (aliases attb)
    u16* Wqkh  = (u16*)w;  w += (size_t)128 * EE * 2;              // 128 KB
    u16* Wqkl  = (u16*)w;  w += (size_t)128 * EE * 2;              // 128 KB
    u16* WvT   = (u16*)w;  w += (size_t)EE * EE * 2;               // 512 KB
    u16* WoT   = (u16*)w;  w += (size_t)EE * EE * 2;               // 512 KB
    u16* qf    = (u16*)w;  w += (size_t)BB * HH * SS * 8 * 2;      // 1 MB
    u16* kf    = (u16*)w;  w += (size_t)BB * HH * SS * 8 * 2;      // 1 MB
    u16* VT    = (u16*)w;  w += (size_t)BB * HH * DKK * SS * 2;    // 8 MB
    u16* attb  = xl;   // alias: xl consumed by qk_mfma before attn writes attb
    float* out = (float*)d_out;

    // P1: x -> bf16 hi/lo
    cvt2_kernel<<<dim3(BS * EE / 4 / 256), 256, 0, stream>>>(
        (const float4*)x, (uint2*)xh, (uint2*)xl, BS * EE / 4);
    // P2: Wq/Wk live cols -> packed transposed bf16 hi/lo
    wqk_pack_kernel<<<dim3(128), 256, 0, stream>>>(Wq, Wk, Wqkh, Wqkl);
    // P3: Wv, Wo -> transposed bf16
    wtrans_kernel<<<dim3(8, 8), 256, 0, stream>>>(Wv, WvT);
    wtrans_kernel<<<dim3(8, 8), 256, 0, stream>>>(Wo, WoT);
    // A: Q/K projection (MFMA, 3-pass double-bf16) + cos -> qf/kf f16
    qk_mfma_kernel<<<dim3(BS / 64, 2), 256, 0, stream>>>(
        xh, xl, Wqkh, Wqkl, bq, bk, qf, kf);
    // B: V projection, computed transposed -> VT[bh][d][s] f16 (MFMA bf16)
    mfma_gemm_kernel<1><<<dim3(EE / 64, BS / 64), 256, 0, stream>>>(
        WvT, xh, bv, nullptr, VT);
    // C: attention (k-split, dbuf, 4 waves/SIMD) -> attb bf16 [B*S][E]
    attn_v6_kernel<<<dim3(1024), 256, 0, stream>>>(qf, kf, VT, attb);
    // D: output projection + bias (MFMA bf16, fp32 out)
    mfma_gemm_kernel<0><<<dim3(BS / 64, EE / 64), 256, 0, stream>>>(
        attb, WoT, bo, out, nullptr);
}

// Round 7
// 85.492 us; speedup vs baseline: 5.6904x; 1.0524x over previous
//
#include <hip/hip_runtime.h>
#include <hip/hip_bf16.h>

// Problem constants
#define BB 4
#define SS 2048
#define EE 512
#define HH 8
#define DKK 64
#define NQQ 8
#define BS (BB * SS)   // 8192 rows

typedef __attribute__((ext_vector_type(4))) float f32x4;
typedef __attribute__((ext_vector_type(16))) float f32x16;
typedef _Float16 f16x8 __attribute__((ext_vector_type(8)));
typedef unsigned short u16;
typedef unsigned int u32;

union U4H8 { uint4 u; f16x8 h; };

__device__ __forceinline__ u16 f2h(float f) {
    _Float16 hv = (_Float16)f;
    return *reinterpret_cast<u16*>(&hv);
}
__device__ __forceinline__ float h2f(u16 u) {
    _Float16 h = *reinterpret_cast<_Float16*>(&u);
    return (float)h;
}

// ---------------------------------------------------------------------------
// P1: x fp32 -> xh (f16) + xl (f16 residual).
// ---------------------------------------------------------------------------
__global__ __launch_bounds__(256) void cvt2_kernel(
    const float4* __restrict__ in, uint2* __restrict__ xh, uint2* __restrict__ xl, int n4)
{
    int i = blockIdx.x * 256 + threadIdx.x;
    if (i >= n4) return;
    float4 a = in[i];
    u16 h0 = f2h(a.x), h1 = f2h(a.y), h2 = f2h(a.z), h3 = f2h(a.w);
    u16 l0 = f2h(a.x - h2f(h0)), l1 = f2h(a.y - h2f(h1));
    u16 l2 = f2h(a.z - h2f(h2)), l3 = f2h(a.w - h2f(h3));
    xh[i] = make_uint2((u32)h0 | ((u32)h1 << 16), (u32)h2 | ((u32)h3 << 16));
    xl[i] = make_uint2((u32)l0 | ((u32)l1 << 16), (u32)l2 | ((u32)l3 << 16));
}

// ---------------------------------------------------------------------------
// P2: pack+transpose the 64 live Q/K weight cols each into Wqk[128][512] f16.
// ---------------------------------------------------------------------------
__global__ __launch_bounds__(256) void wqk_pack_kernel(
    const float* __restrict__ Wq, const float* __restrict__ Wk,
    u16* __restrict__ Wh)
{
    const int n = blockIdx.x;                  // 0..127
    const int col = (((n & 63) >> 3) << 6) | (n & 7);
    const float* src = (n < 64) ? Wq : Wk;
    for (int k = threadIdx.x; k < EE; k += 256) {
        Wh[(size_t)n * EE + k] = f2h(src[(size_t)k * EE + col]);
    }
}

// ---------------------------------------------------------------------------
// P3: W [512][512] f32 -> WT [512][512] f16 transposed (for Wv, Wo).
// ---------------------------------------------------------------------------
__global__ __launch_bounds__(256) void wtrans_kernel(
    const float* __restrict__ W, u16* __restrict__ WT)
{
    __shared__ float ts[64][65];
    const int kt0 = blockIdx.x * 64, nt0 = blockIdx.y * 64;
    const int tid = threadIdx.x;
    #pragma unroll
    for (int i = 0; i < 4; ++i) {
        int c = tid + i * 256;
        int kr = c >> 4, nc = (c & 15) * 4;
        float4 t = *reinterpret_cast<const float4*>(&W[(size_t)(kt0 + kr) * EE + nt0 + nc]);
        ts[kr][nc] = t.x; ts[kr][nc + 1] = t.y; ts[kr][nc + 2] = t.z; ts[kr][nc + 3] = t.w;
    }
    __syncthreads();
    const int n = tid >> 2, k0 = (tid & 3) * 16;
    u32 o[8];
    #pragma unroll
    for (int j = 0; j < 8; ++j) {
        o[j] = (u32)f2h(ts[k0 + 2 * j][n]) | ((u32)f2h(ts[k0 + 2 * j + 1][n]) << 16);
    }
    uint4* dst = reinterpret_cast<uint4*>(&WT[(size_t)(nt0 + n) * EE + kt0 + k0]);
    dst[0] = make_uint4(o[0], o[1], o[2], o[3]);
    dst[1] = make_uint4(o[4], o[5], o[6], o[7]);
}

// ---------------------------------------------------------------------------
// QK projection via MFMA, double-f16 (2 passes: xh*W + xl*W).
// Epilogue: cos(proj + bias) in fp32, store f16 to qf/kf [bh][s][8].
// ---------------------------------------------------------------------------
__global__ __launch_bounds__(256) void qk_mfma_kernel(
    const u16* __restrict__ xh, const u16* __restrict__ xl,
    const u16* __restrict__ Wh,
    const float* __restrict__ bq, const float* __restrict__ bk,
    u16* __restrict__ qf, u16* __restrict__ kf)
{
    __shared__ u16 Asl[64 * 64];
    __shared__ u16 Bsl[64 * 64];

    const int tid = threadIdx.x;
    const int lane = tid & 63;
    const int ww = tid >> 6;
    const int wr = ww >> 1, wc = ww & 1;
    const int tx = lane & 15, tyq = lane >> 4;
    const int m0 = blockIdx.x * 64;
    const int isK = blockIdx.y;
    const int nbase = isK * 64;

    const int c0 = tid, c1 = tid + 256;
    const int r0 = c0 >> 3, o0 = (c0 & 7) * 8, d0 = r0 * 64 + (((c0 & 7) ^ (r0 & 7)) * 8);
    const int r1 = c1 >> 3, o1 = (c1 & 7) * 8, d1 = r1 * 64 + (((c1 & 7) ^ (r1 & 7)) * 8);

    uint4 pa0, pa1, pb0, pb1;
    auto ldi = [&](int it) {
        int pass = it >> 3, k0 = (it & 7) * 64;
        const u16* Ab = pass ? xl : xh;
        pa0 = *reinterpret_cast<const uint4*>(&Ab[(size_t)(m0 + r0) * EE + k0 + o0]);
        pb0 = *reinterpret_cast<const uint4*>(&Wh[(size_t)(nbase + r0) * EE + k0 + o0]);
        pa1 = *reinterpret_cast<const uint4*>(&Ab[(size_t)(m0 + r1) * EE + k0 + o1]);
        pb1 = *reinterpret_cast<const uint4*>(&Wh[(size_t)(nbase + r1) * EE + k0 + o1]);
    };
    auto st = [&]() {
        *reinterpret_cast<uint4*>(&Asl[d0]) = pa0;
        *reinterpret_cast<uint4*>(&Bsl[d0]) = pb0;
        *reinterpret_cast<uint4*>(&Asl[d1]) = pa1;
        *reinterpret_cast<uint4*>(&Bsl[d1]) = pb1;
    };

    f32x4 acc[2][2];
    #pragma unroll
    for (int mt = 0; mt < 2; ++mt)
        #pragma unroll
        for (int nt = 0; nt < 2; ++nt) acc[mt][nt] = (f32x4)(0.f);

    const int bkx = tx & 7;
    ldi(0);
    for (int it = 0; it < 16; ++it) {
        __syncthreads();
        st();
        if (it < 15) ldi(it + 1);
        __syncthreads();
        #pragma unroll
        for (int kb = 0; kb < 2; ++kb) {
            f16x8 af[2], bfg[2];
            const int kblk = ((kb * 4 + tyq) ^ bkx) * 8;
            #pragma unroll
            for (int mt = 0; mt < 2; ++mt)
                af[mt] = *reinterpret_cast<const f16x8*>(&Asl[(wr * 32 + mt * 16 + tx) * 64 + kblk]);
            #pragma unroll
            for (int nt = 0; nt < 2; ++nt)
                bfg[nt] = *reinterpret_cast<const f16x8*>(&Bsl[(wc * 32 + nt * 16 + tx) * 64 + kblk]);
            #pragma unroll
            for (int mt = 0; mt < 2; ++mt)
                #pragma unroll
                for (int nt = 0; nt < 2; ++nt)
                    acc[mt][nt] = __builtin_amdgcn_mfma_f32_16x16x32_f16(
                        af[mt], bfg[nt], acc[mt][nt], 0, 0, 0);
        }
    }

    const float* bias = isK ? bk : bq;
    u16* dst = isK ? kf : qf;
    #pragma unroll
    for (int mt = 0; mt < 2; ++mt) {
        #pragma unroll
        for (int nt = 0; nt < 2; ++nt) {
            int nl = wc * 32 + nt * 16 + tx;
            int h = nl >> 3, f = nl & 7;
            float bcol = bias[h * 64 + f];
            #pragma unroll
            for (int r = 0; r < 4; ++r) {
                int s = m0 + wr * 32 + mt * 16 + tyq * 4 + r;
                float c = __cosf(acc[mt][nt][r] + bcol);
                size_t bh = (size_t)((s >> 11) * HH + h);
                dst[(bh * SS + (s & 2047)) * 8 + f] = f2h(c);
            }
        }
    }
}

// ---------------------------------------------------------------------------
// f16 MFMA GEMM: out[m][n] = sum_k A[m][k] * Bm[n][k] (+ bias)
// MODE 0: out fp32 [8192][512], bias[n] (out-proj).
// MODE 1: out f16 VT2 cells: per bh slab, cell layout bakes the tau permute:
//   element (k,d) -> cell = (k>>4)*2 + ((k>>2)&1), slot = (k&3) + 4*((k>>3)&1)
//   addr(u16) = cell*512 + d*8 + slot. Epilogue: LDS retile -> coalesced write.
// ---------------------------------------------------------------------------
template<int MODE>
__global__ __launch_bounds__(256) void mfma_gemm_kernel(
    const u16* __restrict__ A, const u16* __restrict__ Bm,
    const float* __restrict__ bias, float* __restrict__ outf, u16* __restrict__ outb)
{
    __shared__ u16 smem[8448];   // Asl = smem[0..4095], Bsl = smem[4096..8191]
    u16* Asl = smem;
    u16* Bsl = smem + 4096;

    const int tid = threadIdx.x;
    const int lane = tid & 63;
    const int ww = tid >> 6;
    const int wr = ww >> 1, wc = ww & 1;
    const int tx = lane & 15, tyq = lane >> 4;
    const int m0 = blockIdx.x * 64, n0 = blockIdx.y * 64;

    const int c0 = tid, c1 = tid + 256;
    const int r0 = c0 >> 3, o0 = (c0 & 7) * 8, d0 = r0 * 64 + (((c0 & 7) ^ (r0 & 7)) * 8);
    const int r1 = c1 >> 3, o1 = (c1 & 7) * 8, d1 = r1 * 64 + (((c1 & 7) ^ (r1 & 7)) * 8);

    uint4 pa0, pa1, pb0, pb1;
    auto ld = [&](int ks) {
        int k0 = ks * 64;
        pa0 = *reinterpret_cast<const uint4*>(&A [(size_t)(m0 + r0) * EE + k0 + o0]);
        pb0 = *reinterpret_cast<const uint4*>(&Bm[(size_t)(n0 + r0) * EE + k0 + o0]);
        pa1 = *reinterpret_cast<const uint4*>(&A [(size_t)(m0 + r1) * EE + k0 + o1]);
        pb1 = *reinterpret_cast<const uint4*>(&Bm[(size_t)(n0 + r1) * EE + k0 + o1]);
    };
    auto st = [&]() {
        *reinterpret_cast<uint4*>(&Asl[d0]) = pa0;
        *reinterpret_cast<uint4*>(&Bsl[d0]) = pb0;
        *reinterpret_cast<uint4*>(&Asl[d1]) = pa1;
        *reinterpret_cast<uint4*>(&Bsl[d1]) = pb1;
    };

    f32x4 acc[2][2];
    #pragma unroll
    for (int mt = 0; mt < 2; ++mt)
        #pragma unroll
        for (int nt = 0; nt < 2; ++nt) acc[mt][nt] = (f32x4)(0.f);

    const int bkx = tx & 7;
    ld(0);
    for (int ks = 0; ks < 8; ++ks) {
        __syncthreads();
        st();
        if (ks < 7) ld(ks + 1);
        __syncthreads();
        #pragma unroll
        for (int kb = 0; kb < 2; ++kb) {
            f16x8 af[2], bfg[2];
            const int kblk = ((kb * 4 + tyq) ^ bkx) * 8;
            #pragma unroll
            for (int mt = 0; mt < 2; ++mt)
                af[mt] = *reinterpret_cast<const f16x8*>(&Asl[(wr * 32 + mt * 16 + tx) * 64 + kblk]);
            #pragma unroll
            for (int nt = 0; nt < 2; ++nt)
                bfg[nt] = *reinterpret_cast<const f16x8*>(&Bsl[(wc * 32 + nt * 16 + tx) * 64 + kblk]);
            #pragma unroll
            for (int mt = 0; mt < 2; ++mt)
                #pragma unroll
                for (int nt = 0; nt < 2; ++nt)
                    acc[mt][nt] = __builtin_amdgcn_mfma_f32_16x16x32_f16(
                        af[mt], bfg[nt], acc[mt][nt], 0, 0, 0);
        }
    }

    if (MODE == 0) {
        #pragma unroll
        for (int mt = 0; mt < 2; ++mt) {
            #pragma unroll
            for (int nt = 0; nt < 2; ++nt) {
                int gcol = n0 + wc * 32 + nt * 16 + tx;
                float bcol = bias[gcol];
                #pragma unroll
                for (int r = 0; r < 4; ++r) {
                    int grow = m0 + wr * 32 + mt * 16 + tyq * 4 + r;
                    outf[(size_t)grow * EE + gcol] = acc[mt][nt][r] + bcol;
                }
            }
        }
    } else {
        // retile: stage C as L[d_local][k_local] f16 in LDS (stride 66 u16)
        __syncthreads();   // main-loop LDS reads complete before reuse
        #pragma unroll
        for (int mt = 0; mt < 2; ++mt) {
            #pragma unroll
            for (int nt = 0; nt < 2; ++nt) {
                int kl = wc * 32 + nt * 16 + tx;
                #pragma unroll
                for (int r = 0; r < 4; ++r) {
                    int dl = wr * 32 + mt * 16 + tyq * 4 + r;
                    float vb = acc[mt][nt][r] + bias[m0 + dl];
                    smem[dl * 66 + kl] = f2h(vb);
                }
            }
        }
        __syncthreads();
        // writeout: 512 cells of 16B; item = (ci 0..7, d 0..63)
        const size_t slab = (size_t)((n0 >> 11) * HH + (m0 >> 6)) * (SS * DKK);
        const int cell0 = (n0 & 2047) >> 3;
        #pragma unroll
        for (int i = 0; i < 2; ++i) {
            int item = tid + i * 256;
            int d = item & 63, ci = item >> 6;
            int kb = 16 * (ci >> 1) + 4 * (ci & 1);
            u16 g[8];
            #pragma unroll
            for (int j = 0; j < 8; ++j) {
                int klocal = kb + (j & 3) + 8 * (j >> 2);
                g[j] = smem[d * 66 + klocal];
            }
            uint4 p;
            p.x = (u32)g[0] | ((u32)g[1] << 16);
            p.y = (u32)g[2] | ((u32)g[3] << 16);
            p.z = (u32)g[4] | ((u32)g[5] << 16);
            p.w = (u32)g[6] | ((u32)g[7] << 16);
            *reinterpret_cast<uint4*>(&outb[slab + (size_t)(cell0 + ci) * 512 + d * 8]) = p;
        }
    }
}

// ---------------------------------------------------------------------------
// Attention v7: barrier-free, LDS-free main loop. 32x32x16 f16 MFMAs with
// lane-local sim->PV handoff (v5/v6-verified mapping). V read directly from
// L2 in the tau-baked VT2 cell layout: one fully-coalesced 1KB wave load per
// B-fragment (cell = ((K0>>4)+c)*2 + hi; u16 addr = cell*512 + d*8).
// 4 waves = 2 q-sub-blocks x 2 k-slices; register prefetch 1 step ahead for
// both V (4 frags) and K. Slices combine via LDS at the end (2 barriers).
// ---------------------------------------------------------------------------
__global__ __launch_bounds__(256, 4) void attn_v7_kernel(
    const u16* __restrict__ qf, const u16* __restrict__ kf,
    const u16* __restrict__ VT2, u16* __restrict__ attb)
{
    __shared__ float fsh[128 * 33];   // 16.9 KB combine scratch

    const int tid = threadIdx.x;
    const int lane = tid & 63;
    const int wv = tid >> 6;
    const int kslice = wv >> 1;
    const int qw = wv & 1;
    const int l31 = lane & 31;
    const int hi = lane >> 5;

    // XCD-aware swizzle: all 32 q-blocks of a (b,h) on one XCD
    const int bid = blockIdx.x;
    const int xcd = bid & 7, sub = bid >> 3;
    const int bh = (xcd << 2) | (sub >> 5);
    const int q0 = (sub & 31) * 64;

    const u16* __restrict__ qfb = qf + (size_t)bh * SS * 8;
    const u16* __restrict__ kfb = kf + (size_t)bh * SS * 8;
    const u16* __restrict__ V2b = VT2 + (size_t)bh * SS * DKK;

    const uint4 z4 = make_uint4(0u, 0u, 0u, 0u);

    // Q B-frag (loop-invariant): B[k=8hi+j][n=q=l31]; feats 8..15 pad=0
    U4H8 qb;
    qb.u = hi ? z4 : *reinterpret_cast<const uint4*>(&qfb[(size_t)(q0 + qw * 32 + l31) * 8]);
    const f16x8 QB = qb.h;

    f32x16 acc0 = (f32x16)(0.f), acc1 = (f32x16)(0.f);
    float z = 0.f;

    const int ks_off = kslice * 1024;

    // V frag loader: (t, s) -> 4 uint4 [c*2 + dblk]
    auto vld = [&](int t, int s, uint4* dst) {
        const int K0 = ks_off + t * 64 + s * 32;
        #pragma unroll
        for (int c = 0; c < 2; ++c) {
            const size_t cb = (size_t)((((K0 >> 4) + c) << 1) + hi) * 512;
            dst[c * 2]     = *reinterpret_cast<const uint4*>(&V2b[cb + l31 * 8]);
            dst[c * 2 + 1] = *reinterpret_cast<const uint4*>(&V2b[cb + (32 + l31) * 8]);
        }
    };

    U4H8 kc0, kc1, kn0, kn1;
    auto ldk = [&](int t, U4H8& a, U4H8& b) {
        int kt = ks_off + t * 64;
        a.u = hi ? z4 : *reinterpret_cast<const uint4*>(&kfb[(size_t)(kt + l31) * 8]);
        b.u = hi ? z4 : *reinterpret_cast<const uint4*>(&kfb[(size_t)(kt + 32 + l31) * 8]);
    };

    uint4 vA[4], vB[4];
    ldk(0, kc0, kc1);
    vld(0, 0, vA);

    for (int t = 0; t < 16; ++t) {
        // ---- s = 0 (uses kc0, vA) ----
        vld(t, 1, vB);
        if (t < 15) ldk(t + 1, kn0, kn1);
        {
            f32x16 sim = (f32x16)(0.f);
            sim = __builtin_amdgcn_mfma_f32_32x32x16_f16(kc0.h, QB, sim, 0, 0, 0);
            float w[16];
            #pragma unroll
            for (int r = 0; r < 16; ++r) w[r] = __expf(sim[r]);   // sim in [-8,8]
            float zp = 0.f;
            #pragma unroll
            for (int r = 0; r < 8; ++r) zp += (w[2 * r] + w[2 * r + 1]);
            z += zp;
            #pragma unroll
            for (int c = 0; c < 2; ++c) {
                f16x8 PA;
                #pragma unroll
                for (int j = 0; j < 8; ++j) PA[j] = (_Float16)w[8 * c + j];
                U4H8 b0, b1; b0.u = vA[c * 2]; b1.u = vA[c * 2 + 1];
                acc0 = __builtin_amdgcn_mfma_f32_32x32x16_f16(PA, b0.h, acc0, 0, 0, 0);
                acc1 = __builtin_amdgcn_mfma_f32_32x32x16_f16(PA, b1.h, acc1, 0, 0, 0);
            }
        }
        // ---- s = 1 (uses kc1, vB) ----
        if (t < 15) vld(t + 1, 0, vA);
        {
            f32x16 sim = (f32x16)(0.f);
            sim = __builtin_amdgcn_mfma_f32_32x32x16_f16(kc1.h, QB, sim, 0, 0, 0);
            float w[16];
            #pragma unroll
            for (int r = 0; r < 16; ++r) w[r] = __expf(sim[r]);
            float zp = 0.f;
            #pragma unroll
            for (int r = 0; r < 8; ++r) zp += (w[2 * r] + w[2 * r + 1]);
            z += zp;
            #pragma unroll
            for (int c = 0; c < 2; ++c) {
                f16x8 PA;
                #pragma unroll
                for (int j = 0; j < 8; ++j) PA[j] = (_Float16)w[8 * c + j];
                U4H8 b0, b1; b0.u = vB[c * 2]; b1.u = vB[c * 2 + 1];
                acc0 = __builtin_amdgcn_mfma_f32_32x32x16_f16(PA, b0.h, acc0, 0, 0, 0);
                acc1 = __builtin_amdgcn_mfma_f32_32x32x16_f16(PA, b1.h, acc1, 0, 0, 0);
            }
        }
        kc0 = kn0; kc1 = kn1;
    }

    // combine k-slices via LDS (stride 33 = conflict-free)
    const int cbase = (qw * 64 + lane) * 33;
    if (kslice == 1) {
        #pragma unroll
        for (int r = 0; r < 16; ++r) {
            fsh[cbase + r] = acc0[r];
            fsh[cbase + 16 + r] = acc1[r];
        }
        fsh[cbase + 32] = z;
    }
    __syncthreads();
    if (kslice == 0) {
        #pragma unroll
        for (int r = 0; r < 16; ++r) {
            acc0[r] += fsh[cbase + r];
            acc1[r] += fsh[cbase + 16 + r];
        }
        z += fsh[cbase + 32];
        z += __shfl_xor(z, 32, 64);     // combine hi halves
        float zinv = 1.0f / z;

        const int b = bh >> 3, h = bh & 7;
        #pragma unroll
        for (int r = 0; r < 16; ++r) {
            int qrow = (r & 3) + 8 * (r >> 2) + 4 * hi;
            float zi = __shfl(zinv, qrow, 32);
            size_t base = ((size_t)b * SS + q0 + qw * 32 + qrow) * EE + h * DKK + l31;
            attb[base]      = f2h(acc0[r] * zi);
            attb[base + 32] = f2h(acc1[r] * zi);
        }
    }
}

// ---------------------------------------------------------------------------
extern "C" void kernel_launch(void* const* d_in, const int* in_sizes, int n_in,
                              void* d_out, int out_size, void* d_ws, size_t ws_size,
                              hipStream_t stream)
{
    const float* x  = (const float*)d_in[0];
    const float* Wq = (const float*)d_in[1];
    const float* bq = (const float*)d_in[2];
    const float* Wk = (const float*)d_in[3];
    const float* bk = (const float*)d_in[4];
    const float* Wv = (const float*)d_in[5];
    const float* bv = (const float*)d_in[6];
    const float* Wo = (const float*)d_in[7];
    const float* bo = (const float*)d_in[8];
    // d_in[9] = kernel_params: unused (quantum circuit collapses to cos())

    char* w = (char*)d_ws;
    u16* xh    = (u16*)w;  w += (size_t)BS * EE * 2;               // 8 MB
    u16* xl    = (u16*)w;  w += (size_t)BS * EE * 2;               // 8 MB (aliases attb)
    u16* Wqk   = (u16*)w;  w += (size_t)128 * EE * 2;              // 128 KB
    u16* WvT   = (u16*)w;  w += (size_t)EE * EE * 2;               // 512 KB
    u16* WoT   = (u16*)w;  w += (size_t)EE * EE * 2;               // 512 KB
    u16* qf    = (u16*)w;  w += (size_t)BB * HH * SS * 8 * 2;      // 1 MB
    u16* kf    = (u16*)w;  w += (size_t)BB * HH * SS * 8 * 2;      // 1 MB
    u16* VT2   = (u16*)w;  w += (size_t)BB * HH * DKK * SS * 2;    // 8 MB
    u16* attb  = xl;   // alias: xl consumed by qk_mfma before attn writes attb
    float* out = (float*)d_out;

    // P1: x -> f16 hi/lo
    cvt2_kernel<<<dim3(BS * EE / 4 / 256), 256, 0, stream>>>(
        (const float4*)x, (uint2*)xh, (uint2*)xl, BS * EE / 4);
    // P2: Wq/Wk live cols -> packed transposed f16
    wqk_pack_kernel<<<dim3(128), 256, 0, stream>>>(Wq, Wk, Wqk);
    // P3: Wv, Wo -> transposed f16
    wtrans_kernel<<<dim3(8, 8), 256, 0, stream>>>(Wv, WvT);
    wtrans_kernel<<<dim3(8, 8), 256, 0, stream>>>(Wo, WoT);
    // A: Q/K projection (MFMA, 2-pass double-f16) + cos -> qf/kf f16
    qk_mfma_kernel<<<dim3(BS / 64, 2), 256, 0, stream>>>(
        xh, xl, Wqk, bq, bk, qf, kf);
    // B: V projection -> VT2 tau-baked cell layout (f16 MFMA + LDS retile)
    mfma_gemm_kernel<1><<<dim3(EE / 64, BS / 64), 256, 0, stream>>>(
        WvT, xh, bv, nullptr, VT2);
    // C: attention (barrier-free, direct-L2 VT2 streaming) -> attb f16
    attn_v7_kernel<<<dim3(1024), 256, 0, stream>>>(qf, kf, VT2, attb);
    // D: output projection + bias (f16 MFMA, fp32 out)
    mfma_gemm_kernel<0><<<dim3(BS / 64, EE / 64), 256, 0, stream>>>(
        attb, WoT, bo, out, nullptr);
}